// Round 1
// baseline (911.063 us; speedup 1.0000x reference)
//
#include <hip/hip_runtime.h>

namespace {
constexpr int kS   = 1024;
constexpr int kD   = 512;
constexpr int kH   = 8;
constexpr int kDFF = 2048;
constexpr int kNF  = 85;   // D//6

constexpr int BM = 64, BN = 64, BK = 16;
constexpr int PAD = 68;    // LDS row pad (float4-aligned, conflict-light)
}

// ---------------- small reduction helpers ----------------
__device__ __forceinline__ float wave_sum(float v) {
#pragma unroll
    for (int o = 1; o < 64; o <<= 1) v += __shfl_xor(v, o, 64);
    return v;
}
__device__ __forceinline__ float wave_max(float v) {
#pragma unroll
    for (int o = 1; o < 64; o <<= 1) v = fmaxf(v, __shfl_xor(v, o, 64));
    return v;
}

// ---------------- input projection + positional encoding ----------------
__global__ __launch_bounds__(256)
void input_pe_k(const float* __restrict__ feat, const float* __restrict__ pos,
                const float* __restrict__ fb, const float* __restrict__ in_w,
                const float* __restrict__ in_b, float* __restrict__ x)
{
    int s = blockIdx.x;
    int t = threadIdx.x;
    __shared__ float f[64];
    if (t < 64) f[t] = feat[s * 64 + t];
    __syncthreads();
    float acc0 = in_b[t], acc1 = in_b[t + 256];
#pragma unroll 8
    for (int c = 0; c < 64; ++c) {
        float fv = f[c];
        acc0 = fmaf(fv, in_w[c * kD + t], acc0);
        acc1 = fmaf(fv, in_w[c * kD + 256 + t], acc1);
    }
    float pe0 = 0.f, pe1 = 0.f;
    {
        int d = t;
        if (d < 6 * kNF) {
            int seg = d / kNF, idx = d - seg * kNF;
            float cs = pos[s * 3 + (seg >> 1)] * fb[idx];
            pe0 = (seg & 1) ? cosf(cs) : sinf(cs);
        }
        d = t + 256;
        if (d < 6 * kNF) {
            int seg = d / kNF, idx = d - seg * kNF;
            float cs = pos[s * 3 + (seg >> 1)] * fb[idx];
            pe1 = (seg & 1) ? cosf(cs) : sinf(cs);
        }
    }
    x[s * kD + t]       = acc0 + pe0;
    x[s * kD + 256 + t] = acc1 + pe1;
}

// ---------------- pairwise distance matrix ----------------
__global__ __launch_bounds__(256)
void dist_k(const float* __restrict__ pos, float* __restrict__ dist)
{
    int i = blockIdx.x;
    float px = pos[i * 3], py = pos[i * 3 + 1], pz = pos[i * 3 + 2];
    for (int j = threadIdx.x; j < kS; j += 256) {
        float dx = px - pos[j * 3], dy = py - pos[j * 3 + 1], dz = pz - pos[j * 3 + 2];
        float sq = dx * dx + dy * dy + dz * dz;
        dist[(long)i * kS + j] = sq > 0.f ? sqrtf(sq) : 0.f;
    }
}

// ---------------- exact PWL factorization of the distance-bias MLP ----------------
// bias_h(t) = sum_c relu(a_c t + b_c) w2[c][h] + b2[h]  is piecewise linear in t.
// Build sorted breakpoints + per-segment (A,B) with  bias = A*t + B.
__global__ __launch_bounds__(256)
void pwl_build_k(const float* __restrict__ a_, const float* __restrict__ b_,
                 const float* __restrict__ w2, const float* __restrict__ b2,
                 float* __restrict__ bp_out, float* __restrict__ Atab, float* __restrict__ Btab)
{
    __shared__ float key[128], av[128], bv[128];
    int t = threadIdx.x;
    if (t < 128) {
        float a = a_[t], b = b_[t];
        av[t] = a; bv[t] = b;
        key[t] = (a != 0.f) ? (-b / a) : 3.0e38f;
    }
    __syncthreads();
    // bitonic sort of key[128]
    for (int ksz = 2; ksz <= 128; ksz <<= 1) {
        for (int j = ksz >> 1; j > 0; j >>= 1) {
            if (t < 128) {
                int ixj = t ^ j;
                if (ixj > t) {
                    bool up = ((t & ksz) == 0);
                    float x0 = key[t], x1 = key[ixj];
                    if ((x0 > x1) == up) { key[t] = x1; key[ixj] = x0; }
                }
            }
            __syncthreads();
        }
    }
    if (t < 128) bp_out[t] = key[t];
    __syncthreads();
    for (int task = t; task < 129 * 8; task += 256) {
        int seg = task >> 3, h = task & 7;
        float m;
        if (seg == 0)        m = key[0] - 1.0f;
        else if (seg == 128) m = key[127] + 1.0f;
        else                 m = 0.5f * (key[seg - 1] + key[seg]);
        float A = 0.f, B = 0.f;
        for (int c = 0; c < 128; ++c) {
            float a = av[c], b = bv[c];
            if (fmaf(a, m, b) > 0.f) {
                float w = w2[c * 8 + h];
                A = fmaf(a, w, A);
                B = fmaf(b, w, B);
            }
        }
        Atab[seg * 8 + h] = A;
        Btab[seg * 8 + h] = B + b2[h];
    }
}

// ---------------- generic fp32 tiled GEMM ----------------
// C[z] = A[z] (MxK) @ B[z] (KxN or NxK if TRANSB) with epilogue:
//   EPI 0: + bias (if non-null)
//   EPI 1: + bias, relu
//   EPI 2: * scale + PWL-bias(dist[m][n], head=z)
// z selects among up to 3 distinct pointers then applies the per-z stride.
template <int TRANSB, int EPI>
__global__ __launch_bounds__(256)
void gemm_k(const float* __restrict__ A,
            const float* __restrict__ B0, const float* __restrict__ B1, const float* __restrict__ B2,
            const float* __restrict__ bias0, const float* __restrict__ bias1, const float* __restrict__ bias2,
            float* __restrict__ C0, float* __restrict__ C1, float* __restrict__ C2,
            int M, int N, int K, int lda, int ldb, int ldc,
            long sA, long sB, long sC,
            const float* __restrict__ dist, const float* __restrict__ bp,
            const float* __restrict__ Atab, const float* __restrict__ Btab, float scale)
{
    int z = blockIdx.z;
    const float* Ap    = A + (long)z * sA;
    const float* Bp    = ((z == 1) ? B1 : (z == 2) ? B2 : B0) + (long)z * sB;
    const float* biasp = (z == 1) ? bias1 : (z == 2) ? bias2 : bias0;
    float* Cp          = ((z == 1) ? C1 : (z == 2) ? C2 : C0) + (long)z * sC;

    __shared__ float As[BK][PAD];
    __shared__ float Bs[BK][PAD];
    __shared__ float bps[128];

    int tid = threadIdx.x;
    if (EPI == 2 && tid < 128) bps[tid] = bp[tid];

    int bm = blockIdx.x * BM;
    int bn = blockIdx.y * BN;
    int tx = tid & 15;   // n-dim micro index
    int ty = tid >> 4;   // m-dim micro index

    float acc[4][4] = {};

    for (int k0 = 0; k0 < K; k0 += BK) {
        {   // A tile: As[k][m], float4 along k
            int m  = tid >> 2;
            int kq = (tid & 3) << 2;
            float4 a4 = *reinterpret_cast<const float4*>(Ap + (long)(bm + m) * lda + k0 + kq);
            As[kq + 0][m] = a4.x; As[kq + 1][m] = a4.y;
            As[kq + 2][m] = a4.z; As[kq + 3][m] = a4.w;
        }
        if constexpr (TRANSB) {   // Bs[k][n] = B[n][k]
            int kk2 = tid & 15;
            int n   = tid >> 4;
#pragma unroll
            for (int i = 0; i < 4; ++i)
                Bs[kk2][n + 16 * i] = Bp[(long)(bn + n + 16 * i) * ldb + k0 + kk2];
        } else {                  // Bs[k][n] = B[k][n], float4 along n
            int n4  = (tid & 15) << 2;
            int kb_ = tid >> 4;
            float4 b4 = *reinterpret_cast<const float4*>(Bp + (long)(k0 + kb_) * ldb + bn + n4);
            *reinterpret_cast<float4*>(&Bs[kb_][n4]) = b4;
        }
        __syncthreads();
#pragma unroll
        for (int kk = 0; kk < BK; ++kk) {
            float4 a4 = *reinterpret_cast<const float4*>(&As[kk][ty * 4]);
            float4 b4 = *reinterpret_cast<const float4*>(&Bs[kk][tx * 4]);
            float a[4] = {a4.x, a4.y, a4.z, a4.w};
            float b[4] = {b4.x, b4.y, b4.z, b4.w};
#pragma unroll
            for (int i = 0; i < 4; ++i)
#pragma unroll
                for (int j = 0; j < 4; ++j)
                    acc[i][j] = fmaf(a[i], b[j], acc[i][j]);
        }
        __syncthreads();
    }

#pragma unroll
    for (int i = 0; i < 4; ++i) {
        int m = bm + ty * 4 + i;
        float vals[4];
#pragma unroll
        for (int j = 0; j < 4; ++j) {
            int n = bn + tx * 4 + j;
            float v = acc[i][j];
            if (EPI == 0) {
                if (biasp) v += biasp[n];
            } else if (EPI == 1) {
                v = fmaxf(v + biasp[n], 0.f);
            } else if (EPI == 2) {
                float t = dist[(long)m * kS + n];
                int lo = 0, hi = 128;
                while (lo < hi) { int mid = (lo + hi) >> 1; if (bps[mid] < t) lo = mid + 1; else hi = mid; }
                v = fmaf(v, scale, fmaf(Atab[lo * 8 + z], t, Btab[lo * 8 + z]));
            }
            vals[j] = v;
        }
        *reinterpret_cast<float4*>(&Cp[(long)m * ldc + bn + tx * 4]) =
            make_float4(vals[0], vals[1], vals[2], vals[3]);
    }
}

// ---------------- row softmax over 1024 columns (in place) ----------------
__global__ __launch_bounds__(256)
void softmax_k(float* __restrict__ p)
{
    __shared__ float sm[4];
    long row = blockIdx.x;
    float4* r = reinterpret_cast<float4*>(p + row * (long)kS);
    int t = threadIdx.x;
    float4 v = r[t];
    float m = fmaxf(fmaxf(v.x, v.y), fmaxf(v.z, v.w));
    m = wave_max(m);
    if ((t & 63) == 0) sm[t >> 6] = m;
    __syncthreads();
    m = fmaxf(fmaxf(sm[0], sm[1]), fmaxf(sm[2], sm[3]));
    float e0 = __expf(v.x - m), e1 = __expf(v.y - m), e2 = __expf(v.z - m), e3 = __expf(v.w - m);
    float s = e0 + e1 + e2 + e3;
    __syncthreads();
    s = wave_sum(s);
    if ((t & 63) == 0) sm[t >> 6] = s;
    __syncthreads();
    s = sm[0] + sm[1] + sm[2] + sm[3];
    float inv = 1.0f / s;
    r[t] = make_float4(e0 * inv, e1 * inv, e2 * inv, e3 * inv);
}

// ---------------- residual add + layernorm (in place on x) ----------------
__global__ __launch_bounds__(256)
void add_ln_k(float* __restrict__ x, const float* __restrict__ y,
              const float* __restrict__ g, const float* __restrict__ b)
{
    __shared__ float sm[4];
    int row = blockIdx.x, t = threadIdx.x;
    float* xr = x + (long)row * kD;
    const float* yr = y + (long)row * kD;
    float s0 = xr[t] + yr[t];
    float s1 = xr[t + 256] + yr[t + 256];
    float sum = wave_sum(s0 + s1);
    if ((t & 63) == 0) sm[t >> 6] = sum;
    __syncthreads();
    sum = sm[0] + sm[1] + sm[2] + sm[3];
    float mu = sum * (1.f / kD);
    float d0 = s0 - mu, d1 = s1 - mu;
    __syncthreads();
    float vs = wave_sum(d0 * d0 + d1 * d1);
    if ((t & 63) == 0) sm[t >> 6] = vs;
    __syncthreads();
    vs = sm[0] + sm[1] + sm[2] + sm[3];
    float rs = rsqrtf(vs * (1.f / kD) + 1e-5f);
    xr[t]       = fmaf(d0 * rs, g[t], b[t]);
    xr[t + 256] = fmaf(d1 * rs, g[t + 256], b[t + 256]);
}

// ---------------- mean-pool partials ----------------
__global__ __launch_bounds__(256)
void pool_k(const float* __restrict__ x, float* __restrict__ partial)
{
    int col = blockIdx.x * 256 + threadIdx.x;
    int rb = blockIdx.y;
    float s = 0.f;
    for (int r = rb * 128; r < rb * 128 + 128; ++r) s += x[(long)r * kD + col];
    partial[rb * kD + col] = s;
}

// ---------------- classifier head ----------------
__global__ __launch_bounds__(256)
void head_k(const float* __restrict__ partial,
            const float* __restrict__ c1w, const float* __restrict__ c1b,
            const float* __restrict__ c2w, const float* __restrict__ c2b,
            float* __restrict__ out)
{
    __shared__ float pooled[kD];
    __shared__ float h1[256];
    int t = threadIdx.x;
    for (int d = t; d < kD; d += 256) {
        float s = 0.f;
        for (int r = 0; r < 8; ++r) s += partial[r * kD + d];
        pooled[d] = s * (1.0f / kS);
    }
    __syncthreads();
    float acc = c1b[t];
    for (int f = 0; f < kD; ++f) acc = fmaf(pooled[f], c1w[f * 256 + t], acc);
    h1[t] = fmaxf(acc, 0.f);
    __syncthreads();
    if (t < 10) {
        float o = c2b[t];
        for (int f = 0; f < 256; ++f) o = fmaf(h1[f], c2w[f * 10 + t], o);
        out[t] = o;
    }
}

// ---------------- launch ----------------
extern "C" void kernel_launch(void* const* d_in, const int* in_sizes, int n_in,
                              void* d_out, int out_size, void* d_ws, size_t ws_size,
                              hipStream_t stream)
{
    (void)in_sizes; (void)n_in; (void)out_size; (void)ws_size;
    const float* features = (const float*)d_in[0];
    const float* positions= (const float*)d_in[1];
    const float* fb       = (const float*)d_in[2];
    const float* in_w     = (const float*)d_in[3];
    const float* in_b     = (const float*)d_in[4];
    const float* qw  = (const float*)d_in[5];
    const float* qb  = (const float*)d_in[6];
    const float* kw  = (const float*)d_in[7];
    const float* kb  = (const float*)d_in[8];
    const float* vw  = (const float*)d_in[9];
    const float* vb  = (const float*)d_in[10];
    const float* ow  = (const float*)d_in[11];
    const float* ob  = (const float*)d_in[12];
    const float* db1w= (const float*)d_in[13];
    const float* db1b= (const float*)d_in[14];
    const float* db2w= (const float*)d_in[15];
    const float* db2b= (const float*)d_in[16];
    const float* n1g = (const float*)d_in[17];
    const float* n1b = (const float*)d_in[18];
    const float* n2g = (const float*)d_in[19];
    const float* n2b = (const float*)d_in[20];
    const float* f1w = (const float*)d_in[21];
    const float* f1b = (const float*)d_in[22];
    const float* f2w = (const float*)d_in[23];
    const float* f2b = (const float*)d_in[24];
    const float* c1w = (const float*)d_in[25];
    const float* c1b = (const float*)d_in[26];
    const float* c2w = (const float*)d_in[27];
    const float* c2b = (const float*)d_in[28];

    float* ws = (float*)d_ws;
    const long SD = (long)kS * kD;           // 524288
    float* x      = ws;
    float* q      = ws + 1 * SD;
    float* kbuf   = ws + 2 * SD;
    float* v      = ws + 3 * SD;
    float* ao     = ws + 4 * SD;
    float* y      = ws + 5 * SD;
    float* hbuf   = ws + 6 * SD;             // S*DFF = 2097152
    float* dist   = hbuf + (long)kS * kDFF;
    float* scores = dist + (long)kS * kS;    // H*S*S = 8388608
    float* bpw    = scores + (long)kH * kS * kS;
    float* Atab   = bpw + 128;
    float* Btab   = Atab + 1040;
    float* partial= Btab + 1040;

    input_pe_k<<<kS, 256, 0, stream>>>(features, positions, fb, in_w, in_b, x);
    dist_k<<<kS, 256, 0, stream>>>(positions, dist);

    const long SS = (long)kS * kS;
    for (int l = 0; l < 2; ++l) {
        const float* qwl = qw + (long)l * kD * kD;
        const float* kwl = kw + (long)l * kD * kD;
        const float* vwl = vw + (long)l * kD * kD;
        const float* owl = ow + (long)l * kD * kD;

        pwl_build_k<<<1, 256, 0, stream>>>(db1w + l * 128, db1b + l * 128,
                                           db2w + l * 128 * 8, db2b + l * 8,
                                           bpw, Atab, Btab);
        // fused QKV: z selects weight/bias/output
        gemm_k<0, 0><<<dim3(16, 8, 3), 256, 0, stream>>>(
            x, qwl, kwl, vwl, qb + l * kD, kb + l * kD, vb + l * kD,
            q, kbuf, v, kS, kD, kD, kD, kD, kD, 0, 0, 0,
            nullptr, nullptr, nullptr, nullptr, 0.f);
        // scores = (q @ k^T) * scale + PWL-bias, batched over heads
        gemm_k<1, 2><<<dim3(16, 16, 8), 256, 0, stream>>>(
            q, kbuf, kbuf, kbuf, nullptr, nullptr, nullptr,
            scores, scores, scores, kS, kS, 64, kD, kD, kS, 64, 64, SS,
            dist, bpw, Atab, Btab, 0.125f);
        softmax_k<<<kH * kS, 256, 0, stream>>>(scores);
        // attn @ v, batched over heads
        gemm_k<0, 0><<<dim3(16, 1, 8), 256, 0, stream>>>(
            scores, v, v, v, nullptr, nullptr, nullptr,
            ao, ao, ao, kS, 64, kS, kS, kD, kD, SS, 64, 64,
            nullptr, nullptr, nullptr, nullptr, 0.f);
        // output projection
        gemm_k<0, 0><<<dim3(16, 8, 1), 256, 0, stream>>>(
            ao, owl, owl, owl, ob + l * kD, ob + l * kD, ob + l * kD,
            y, y, y, kS, kD, kD, kD, kD, kD, 0, 0, 0,
            nullptr, nullptr, nullptr, nullptr, 0.f);
        add_ln_k<<<kS, 256, 0, stream>>>(x, y, n1g + l * kD, n1b + l * kD);
        // FFN
        const float* f1wl = f1w + (long)l * kD * kDFF;
        const float* f2wl = f2w + (long)l * kDFF * kD;
        gemm_k<0, 1><<<dim3(16, 32, 1), 256, 0, stream>>>(
            x, f1wl, f1wl, f1wl, f1b + l * kDFF, f1b + l * kDFF, f1b + l * kDFF,
            hbuf, hbuf, hbuf, kS, kDFF, kD, kD, kDFF, kDFF, 0, 0, 0,
            nullptr, nullptr, nullptr, nullptr, 0.f);
        gemm_k<0, 0><<<dim3(16, 8, 1), 256, 0, stream>>>(
            hbuf, f2wl, f2wl, f2wl, f2b + l * kD, f2b + l * kD, f2b + l * kD,
            y, y, y, kS, kD, kDFF, kDFF, kD, kD, 0, 0, 0,
            nullptr, nullptr, nullptr, nullptr, 0.f);
        add_ln_k<<<kS, 256, 0, stream>>>(x, y, n2g + l * kD, n2b + l * kD);
    }

    pool_k<<<dim3(2, 8), 256, 0, stream>>>(x, partial);
    head_k<<<1, 256, 0, stream>>>(partial, c1w, c1b, c2w, c2b, (float*)d_out);
}

// Round 2
// 671.273 us; speedup vs baseline: 1.3572x; 1.3572x over previous
//
#include <hip/hip_runtime.h>

namespace {
constexpr int kS   = 1024;
constexpr int kD   = 512;
constexpr int kH   = 8;
constexpr int kDFF = 2048;
constexpr int kNF  = 85;   // D//6

constexpr int BM = 64, BN = 64, BK = 16;
constexpr int PAD = 68;    // LDS row pad
}

// ---------------- small reduction helpers ----------------
__device__ __forceinline__ float wave_sum(float v) {
#pragma unroll
    for (int o = 1; o < 64; o <<= 1) v += __shfl_xor(v, o, 64);
    return v;
}
__device__ __forceinline__ float wave_max(float v) {
#pragma unroll
    for (int o = 1; o < 64; o <<= 1) v = fmaxf(v, __shfl_xor(v, o, 64));
    return v;
}

// ---------------- input projection + positional encoding ----------------
__global__ __launch_bounds__(256)
void input_pe_k(const float* __restrict__ feat, const float* __restrict__ pos,
                const float* __restrict__ fb, const float* __restrict__ in_w,
                const float* __restrict__ in_b, float* __restrict__ x)
{
    int s = blockIdx.x;
    int t = threadIdx.x;
    __shared__ float f[64];
    if (t < 64) f[t] = feat[s * 64 + t];
    __syncthreads();
    float acc0 = in_b[t], acc1 = in_b[t + 256];
#pragma unroll 8
    for (int c = 0; c < 64; ++c) {
        float fv = f[c];
        acc0 = fmaf(fv, in_w[c * kD + t], acc0);
        acc1 = fmaf(fv, in_w[c * kD + 256 + t], acc1);
    }
    float pe0 = 0.f, pe1 = 0.f;
    {
        int d = t;
        if (d < 6 * kNF) {
            int seg = d / kNF, idx = d - seg * kNF;
            float cs = pos[s * 3 + (seg >> 1)] * fb[idx];
            pe0 = (seg & 1) ? cosf(cs) : sinf(cs);
        }
        d = t + 256;
        if (d < 6 * kNF) {
            int seg = d / kNF, idx = d - seg * kNF;
            float cs = pos[s * 3 + (seg >> 1)] * fb[idx];
            pe1 = (seg & 1) ? cosf(cs) : sinf(cs);
        }
    }
    x[s * kD + t]       = acc0 + pe0;
    x[s * kD + 256 + t] = acc1 + pe1;
}

// ---------------- pairwise distance matrix ----------------
__global__ __launch_bounds__(256)
void dist_k(const float* __restrict__ pos, float* __restrict__ dist)
{
    int i = blockIdx.x;
    float px = pos[i * 3], py = pos[i * 3 + 1], pz = pos[i * 3 + 2];
    for (int j = threadIdx.x; j < kS; j += 256) {
        float dx = px - pos[j * 3], dy = py - pos[j * 3 + 1], dz = pz - pos[j * 3 + 2];
        float sq = dx * dx + dy * dy + dz * dz;
        dist[(long)i * kS + j] = sq > 0.f ? sqrtf(sq) : 0.f;
    }
}

// ---------------- exact PWL factorization of the distance-bias MLP ----------------
__global__ __launch_bounds__(256)
void pwl_build_k(const float* __restrict__ a_, const float* __restrict__ b_,
                 const float* __restrict__ w2, const float* __restrict__ b2,
                 float* __restrict__ bp_out, float* __restrict__ Atab, float* __restrict__ Btab)
{
    __shared__ float key[128], av[128], bv[128];
    int t = threadIdx.x;
    if (t < 128) {
        float a = a_[t], b = b_[t];
        av[t] = a; bv[t] = b;
        key[t] = (a != 0.f) ? (-b / a) : 3.0e38f;
    }
    __syncthreads();
    for (int ksz = 2; ksz <= 128; ksz <<= 1) {
        for (int j = ksz >> 1; j > 0; j >>= 1) {
            if (t < 128) {
                int ixj = t ^ j;
                if (ixj > t) {
                    bool up = ((t & ksz) == 0);
                    float x0 = key[t], x1 = key[ixj];
                    if ((x0 > x1) == up) { key[t] = x1; key[ixj] = x0; }
                }
            }
            __syncthreads();
        }
    }
    if (t < 128) bp_out[t] = key[t];
    __syncthreads();
    for (int task = t; task < 129 * 8; task += 256) {
        int seg = task >> 3, h = task & 7;
        float m;
        if (seg == 0)        m = key[0] - 1.0f;
        else if (seg == 128) m = key[127] + 1.0f;
        else                 m = 0.5f * (key[seg - 1] + key[seg]);
        float A = 0.f, B = 0.f;
        for (int c = 0; c < 128; ++c) {
            float a = av[c], b = bv[c];
            if (fmaf(a, m, b) > 0.f) {
                float w = w2[c * 8 + h];
                A = fmaf(a, w, A);
                B = fmaf(b, w, B);
            }
        }
        Atab[seg * 8 + h] = A;
        Btab[seg * 8 + h] = B + b2[h];
    }
}

// ---------------- generic fp32 tiled GEMM (register-prefetch double buffered) ----
// SPLIT==0: C[z] = A[z] @ B[z]  with epilogue EPI (0 bias, 1 bias+relu, 2 scale+PWL)
// SPLIT==1: K arg is K-per-slice; blockIdx.z = z*splitk+ks; plain partial store to
//           Cpart[bz][M][N]; epilogue deferred to reduce_k.
template <int TRANSB, int EPI, int SPLIT>
__global__ __launch_bounds__(256)
void gemm_k(const float* __restrict__ A,
            const float* __restrict__ B0, const float* __restrict__ B1, const float* __restrict__ B2,
            const float* __restrict__ bias0, const float* __restrict__ bias1, const float* __restrict__ bias2,
            float* __restrict__ C0, float* __restrict__ C1, float* __restrict__ C2,
            int M, int N, int K, int lda, int ldb, int ldc,
            long sA, long sB, long sC, int splitk,
            const float* __restrict__ dist, const float* __restrict__ bp,
            const float* __restrict__ Atab, const float* __restrict__ Btab, float scale,
            float* __restrict__ Cpart)
{
    int bz = blockIdx.z;
    int z  = SPLIT ? bz / splitk : bz;
    int ks = SPLIT ? bz - (bz / splitk) * splitk : 0;

    const float* Ap = A + (long)z * sA + (SPLIT ? (long)ks * K : 0);
    const float* Bb = ((z == 1) ? B1 : (z == 2) ? B2 : B0) + (long)z * sB;
    const float* Bp = Bb + (SPLIT ? (TRANSB ? (long)ks * K : (long)ks * K * ldb) : 0);

    __shared__ float As[BK][PAD];
    __shared__ float Bs[BK][PAD];
    __shared__ float bps[128];

    int tid = threadIdx.x;
    if (EPI == 2 && !SPLIT && tid < 128) bps[tid] = bp[tid];

    int bm = blockIdx.x * BM;
    int bn = blockIdx.y * BN;
    int tx = tid & 15;
    int ty = tid >> 4;

    // loader lane indices
    int am  = tid >> 2;          // A row within tile
    int akq = (tid & 3) << 2;    // A k quad
    int bn4 = (tid & 15) << 2;   // !TRANSB: n quad
    int bkb = tid >> 4;          // !TRANSB: k row
    int bkk = tid & 15;          // TRANSB: k
    int bnb = tid >> 4;          // TRANSB: n base

    float acc[4][4] = {};
    float4 aReg;
    float4 bReg;
    float  brT[4];

    aReg = *reinterpret_cast<const float4*>(Ap + (long)(bm + am) * lda + akq);
    if constexpr (TRANSB) {
#pragma unroll
        for (int i = 0; i < 4; ++i)
            brT[i] = Bp[(long)(bn + bnb + 16 * i) * ldb + bkk];
    } else {
        bReg = *reinterpret_cast<const float4*>(Bp + (long)bkb * ldb + bn + bn4);
    }

    for (int k0 = 0; k0 < K; k0 += BK) {
        As[akq + 0][am] = aReg.x; As[akq + 1][am] = aReg.y;
        As[akq + 2][am] = aReg.z; As[akq + 3][am] = aReg.w;
        if constexpr (TRANSB) {
#pragma unroll
            for (int i = 0; i < 4; ++i) Bs[bkk][bnb + 16 * i] = brT[i];
        } else {
            *reinterpret_cast<float4*>(&Bs[bkb][bn4]) = bReg;
        }
        __syncthreads();
        if (k0 + BK < K) {   // prefetch next tiles into registers, overlaps compute
            aReg = *reinterpret_cast<const float4*>(Ap + (long)(bm + am) * lda + k0 + BK + akq);
            if constexpr (TRANSB) {
#pragma unroll
                for (int i = 0; i < 4; ++i)
                    brT[i] = Bp[(long)(bn + bnb + 16 * i) * ldb + k0 + BK + bkk];
            } else {
                bReg = *reinterpret_cast<const float4*>(Bp + (long)(k0 + BK + bkb) * ldb + bn + bn4);
            }
        }
#pragma unroll
        for (int kk = 0; kk < BK; ++kk) {
            float4 a4 = *reinterpret_cast<const float4*>(&As[kk][ty * 4]);
            float4 b4 = *reinterpret_cast<const float4*>(&Bs[kk][tx * 4]);
            float a[4] = {a4.x, a4.y, a4.z, a4.w};
            float b[4] = {b4.x, b4.y, b4.z, b4.w};
#pragma unroll
            for (int i = 0; i < 4; ++i)
#pragma unroll
                for (int j = 0; j < 4; ++j)
                    acc[i][j] = fmaf(a[i], b[j], acc[i][j]);
        }
        __syncthreads();
    }

    if constexpr (SPLIT) {
        float* Cp = Cpart + (long)bz * M * N;
#pragma unroll
        for (int i = 0; i < 4; ++i) {
            int m = bm + ty * 4 + i;
            *reinterpret_cast<float4*>(&Cp[(long)m * N + bn + tx * 4]) =
                make_float4(acc[i][0], acc[i][1], acc[i][2], acc[i][3]);
        }
    } else {
        const float* biasp = (z == 1) ? bias1 : (z == 2) ? bias2 : bias0;
        float* Cp = ((z == 1) ? C1 : (z == 2) ? C2 : C0) + (long)z * sC;
#pragma unroll
        for (int i = 0; i < 4; ++i) {
            int m = bm + ty * 4 + i;
            float vals[4];
#pragma unroll
            for (int j = 0; j < 4; ++j) {
                int n = bn + tx * 4 + j;
                float v = acc[i][j];
                if (EPI == 0) {
                    if (biasp) v += biasp[n];
                } else if (EPI == 1) {
                    v = fmaxf(v + biasp[n], 0.f);
                } else if (EPI == 2) {
                    float t = dist[(long)m * kS + n];
                    int lo = 0, hi = 128;
                    while (lo < hi) { int mid = (lo + hi) >> 1; if (bps[mid] < t) lo = mid + 1; else hi = mid; }
                    v = fmaf(v, scale, fmaf(Atab[lo * 8 + z], t, Btab[lo * 8 + z]));
                }
                vals[j] = v;
            }
            *reinterpret_cast<float4*>(&Cp[(long)m * ldc + bn + tx * 4]) =
                make_float4(vals[0], vals[1], vals[2], vals[3]);
        }
    }
}

// ---------------- split-K reduction: sum slices + bias (+relu) ----------------
template <int RELU>
__global__ __launch_bounds__(256)
void reduce_k(const float* __restrict__ part,
              float* __restrict__ C0, float* __restrict__ C1, float* __restrict__ C2,
              const float* __restrict__ bias0, const float* __restrict__ bias1, const float* __restrict__ bias2,
              int M, int N, int splitk, long sC, int ldc)
{
    int z = blockIdx.y;
    long MN = (long)M * N;
    long idx = ((long)blockIdx.x * 256 + threadIdx.x) * 4;
    if (idx >= MN) return;
    const float* pz = part + (long)z * splitk * MN + idx;
    float4 s = *reinterpret_cast<const float4*>(pz);
    for (int t = 1; t < splitk; ++t) {
        float4 v = *reinterpret_cast<const float4*>(pz + (long)t * MN);
        s.x += v.x; s.y += v.y; s.z += v.z; s.w += v.w;
    }
    int m = (int)(idx / N), n = (int)(idx - (long)m * N);
    const float* bzp = (z == 1) ? bias1 : (z == 2) ? bias2 : bias0;
    if (bzp) { s.x += bzp[n]; s.y += bzp[n + 1]; s.z += bzp[n + 2]; s.w += bzp[n + 3]; }
    if (RELU) {
        s.x = fmaxf(s.x, 0.f); s.y = fmaxf(s.y, 0.f);
        s.z = fmaxf(s.z, 0.f); s.w = fmaxf(s.w, 0.f);
    }
    float* Cp = ((z == 1) ? C1 : (z == 2) ? C2 : C0) + (long)z * sC;
    *reinterpret_cast<float4*>(&Cp[(long)m * ldc + n]) = s;
}

// ---------------- row softmax over 1024 columns (in place) ----------------
__global__ __launch_bounds__(256)
void softmax_k(float* __restrict__ p)
{
    __shared__ float sm[4];
    long row = blockIdx.x;
    float4* r = reinterpret_cast<float4*>(p + row * (long)kS);
    int t = threadIdx.x;
    float4 v = r[t];
    float m = fmaxf(fmaxf(v.x, v.y), fmaxf(v.z, v.w));
    m = wave_max(m);
    if ((t & 63) == 0) sm[t >> 6] = m;
    __syncthreads();
    m = fmaxf(fmaxf(sm[0], sm[1]), fmaxf(sm[2], sm[3]));
    float e0 = __expf(v.x - m), e1 = __expf(v.y - m), e2 = __expf(v.z - m), e3 = __expf(v.w - m);
    float s = e0 + e1 + e2 + e3;
    __syncthreads();
    s = wave_sum(s);
    if ((t & 63) == 0) sm[t >> 6] = s;
    __syncthreads();
    s = sm[0] + sm[1] + sm[2] + sm[3];
    float inv = 1.0f / s;
    r[t] = make_float4(e0 * inv, e1 * inv, e2 * inv, e3 * inv);
}

// ---------------- residual add + layernorm (in place on x) ----------------
__global__ __launch_bounds__(256)
void add_ln_k(float* __restrict__ x, const float* __restrict__ y,
              const float* __restrict__ g, const float* __restrict__ b)
{
    __shared__ float sm[4];
    int row = blockIdx.x, t = threadIdx.x;
    float* xr = x + (long)row * kD;
    const float* yr = y + (long)row * kD;
    float s0 = xr[t] + yr[t];
    float s1 = xr[t + 256] + yr[t + 256];
    float sum = wave_sum(s0 + s1);
    if ((t & 63) == 0) sm[t >> 6] = sum;
    __syncthreads();
    sum = sm[0] + sm[1] + sm[2] + sm[3];
    float mu = sum * (1.f / kD);
    float d0 = s0 - mu, d1 = s1 - mu;
    __syncthreads();
    float vs = wave_sum(d0 * d0 + d1 * d1);
    if ((t & 63) == 0) sm[t >> 6] = vs;
    __syncthreads();
    vs = sm[0] + sm[1] + sm[2] + sm[3];
    float rs = rsqrtf(vs * (1.f / kD) + 1e-5f);
    xr[t]       = fmaf(d0 * rs, g[t], b[t]);
    xr[t + 256] = fmaf(d1 * rs, g[t + 256], b[t + 256]);
}

// ---------------- mean-pool partials ----------------
__global__ __launch_bounds__(256)
void pool_k(const float* __restrict__ x, float* __restrict__ partial)
{
    int col = blockIdx.x * 256 + threadIdx.x;
    int rb = blockIdx.y;
    float s = 0.f;
    for (int r = rb * 128; r < rb * 128 + 128; ++r) s += x[(long)r * kD + col];
    partial[rb * kD + col] = s;
}

// ---------------- classifier head ----------------
__global__ __launch_bounds__(256)
void head_k(const float* __restrict__ partial,
            const float* __restrict__ c1w, const float* __restrict__ c1b,
            const float* __restrict__ c2w, const float* __restrict__ c2b,
            float* __restrict__ out)
{
    __shared__ float pooled[kD];
    __shared__ float h1[256];
    int t = threadIdx.x;
    for (int d = t; d < kD; d += 256) {
        float s = 0.f;
        for (int r = 0; r < 8; ++r) s += partial[r * kD + d];
        pooled[d] = s * (1.0f / kS);
    }
    __syncthreads();
    float acc = c1b[t];
    for (int f = 0; f < kD; ++f) acc = fmaf(pooled[f], c1w[f * 256 + t], acc);
    h1[t] = fmaxf(acc, 0.f);
    __syncthreads();
    if (t < 10) {
        float o = c2b[t];
        for (int f = 0; f < 256; ++f) o = fmaf(h1[f], c2w[f * 10 + t], o);
        out[t] = o;
    }
}

// ---------------- launch ----------------
extern "C" void kernel_launch(void* const* d_in, const int* in_sizes, int n_in,
                              void* d_out, int out_size, void* d_ws, size_t ws_size,
                              hipStream_t stream)
{
    (void)in_sizes; (void)n_in; (void)out_size; (void)ws_size;
    const float* features = (const float*)d_in[0];
    const float* positions= (const float*)d_in[1];
    const float* fb       = (const float*)d_in[2];
    const float* in_w     = (const float*)d_in[3];
    const float* in_b     = (const float*)d_in[4];
    const float* qw  = (const float*)d_in[5];
    const float* qb  = (const float*)d_in[6];
    const float* kw  = (const float*)d_in[7];
    const float* kb  = (const float*)d_in[8];
    const float* vw  = (const float*)d_in[9];
    const float* vb  = (const float*)d_in[10];
    const float* ow  = (const float*)d_in[11];
    const float* ob  = (const float*)d_in[12];
    const float* db1w= (const float*)d_in[13];
    const float* db1b= (const float*)d_in[14];
    const float* db2w= (const float*)d_in[15];
    const float* db2b= (const float*)d_in[16];
    const float* n1g = (const float*)d_in[17];
    const float* n1b = (const float*)d_in[18];
    const float* n2g = (const float*)d_in[19];
    const float* n2b = (const float*)d_in[20];
    const float* f1w = (const float*)d_in[21];
    const float* f1b = (const float*)d_in[22];
    const float* f2w = (const float*)d_in[23];
    const float* f2b = (const float*)d_in[24];
    const float* c1w = (const float*)d_in[25];
    const float* c1b = (const float*)d_in[26];
    const float* c2w = (const float*)d_in[27];
    const float* c2b = (const float*)d_in[28];

    float* ws = (float*)d_ws;
    const long SD = (long)kS * kD;           // 524288
    float* x      = ws;
    float* q      = ws + 1 * SD;
    float* kbuf   = ws + 2 * SD;
    float* v      = ws + 3 * SD;
    float* ao     = ws + 4 * SD;
    float* y      = ws + 5 * SD;
    float* hbuf   = ws + 6 * SD;             // S*DFF = 2097152 floats (8 MB)
    float* dist   = hbuf + (long)kS * kDFF;
    float* scores = dist + (long)kS * kS;    // H*S*S = 8388608 floats (32 MB)
    float* bpw    = scores + (long)kH * kS * kS;
    float* Atab   = bpw + 128;
    float* Btab   = Atab + 1040;
    float* partial= Btab + 1040;

    // partial-sum scratch overlays (regions dead at time of use):
    float* part_big = scores;   // QKV / O-proj / FFN1 / FFN2 partials (scores not live)
    float* part_av  = hbuf;     // AV partials (hbuf not live; 32*64K floats = 8 MB fits)

    input_pe_k<<<kS, 256, 0, stream>>>(features, positions, fb, in_w, in_b, x);
    dist_k<<<kS, 256, 0, stream>>>(positions, dist);

    const long SS = (long)kS * kS;
    for (int l = 0; l < 2; ++l) {
        const float* qwl = qw + (long)l * kD * kD;
        const float* kwl = kw + (long)l * kD * kD;
        const float* vwl = vw + (long)l * kD * kD;
        const float* owl = ow + (long)l * kD * kD;

        pwl_build_k<<<1, 256, 0, stream>>>(db1w + l * 128, db1b + l * 128,
                                           db2w + l * 128 * 8, db2b + l * 8,
                                           bpw, Atab, Btab);

        // fused QKV, split-K x2: z in {q,k,v} -> grid.z = 3*2
        gemm_k<0, 0, 1><<<dim3(16, 8, 6), 256, 0, stream>>>(
            x, qwl, kwl, vwl, nullptr, nullptr, nullptr,
            q, kbuf, v, kS, kD, 256, kD, kD, kD, 0, 0, 0, 2,
            nullptr, nullptr, nullptr, nullptr, 0.f, part_big);
        reduce_k<0><<<dim3(512, 3), 256, 0, stream>>>(
            part_big, q, kbuf, v, qb + l * kD, kb + l * kD, vb + l * kD,
            kS, kD, 2, 0, kD);

        // scores = (q @ k^T) * scale + PWL-bias, batched over heads (no split)
        gemm_k<1, 2, 0><<<dim3(16, 16, 8), 256, 0, stream>>>(
            q, kbuf, kbuf, kbuf, nullptr, nullptr, nullptr,
            scores, scores, scores, kS, kS, 64, kD, kD, kS, 64, 64, SS, 1,
            dist, bpw, Atab, Btab, 0.125f, nullptr);
        softmax_k<<<kH * kS, 256, 0, stream>>>(scores);

        // attn @ v, split-K x4 per head -> grid.z = 8*4
        gemm_k<0, 0, 1><<<dim3(16, 1, 32), 256, 0, stream>>>(
            scores, v, v, v, nullptr, nullptr, nullptr,
            ao, ao, ao, kS, 64, 256, kS, kD, kD, SS, 64, 64, 4,
            nullptr, nullptr, nullptr, nullptr, 0.f, part_av);
        reduce_k<0><<<dim3(64, 8), 256, 0, stream>>>(
            part_av, ao, ao, ao, nullptr, nullptr, nullptr,
            kS, 64, 4, 64, kD);

        // output projection, split-K x4
        gemm_k<0, 0, 1><<<dim3(16, 8, 4), 256, 0, stream>>>(
            ao, owl, owl, owl, nullptr, nullptr, nullptr,
            y, y, y, kS, kD, 128, kD, kD, kD, 0, 0, 0, 4,
            nullptr, nullptr, nullptr, nullptr, 0.f, part_big);
        reduce_k<0><<<dim3(512, 1), 256, 0, stream>>>(
            part_big, y, y, y, ob + l * kD, ob + l * kD, ob + l * kD,
            kS, kD, 4, 0, kD);

        add_ln_k<<<kS, 256, 0, stream>>>(x, y, n1g + l * kD, n1b + l * kD);

        // FFN1, split-K x2, relu in reduce
        const float* f1wl = f1w + (long)l * kD * kDFF;
        const float* f2wl = f2w + (long)l * kDFF * kD;
        gemm_k<0, 0, 1><<<dim3(16, 32, 2), 256, 0, stream>>>(
            x, f1wl, f1wl, f1wl, nullptr, nullptr, nullptr,
            hbuf, hbuf, hbuf, kS, kDFF, 256, kD, kDFF, kDFF, 0, 0, 0, 2,
            nullptr, nullptr, nullptr, nullptr, 0.f, part_big);
        reduce_k<1><<<dim3(2048, 1), 256, 0, stream>>>(
            part_big, hbuf, hbuf, hbuf, f1b + l * kDFF, f1b + l * kDFF, f1b + l * kDFF,
            kS, kDFF, 2, 0, kDFF);

        // FFN2, split-K x4
        gemm_k<0, 0, 1><<<dim3(16, 8, 4), 256, 0, stream>>>(
            hbuf, f2wl, f2wl, f2wl, nullptr, nullptr, nullptr,
            y, y, y, kS, kD, 512, kDFF, kD, kD, 0, 0, 0, 4,
            nullptr, nullptr, nullptr, nullptr, 0.f, part_big);
        reduce_k<0><<<dim3(512, 1), 256, 0, stream>>>(
            part_big, y, y, y, f2b + l * kD, f2b + l * kD, f2b + l * kD,
            kS, kD, 4, 0, kD);

        add_ln_k<<<kS, 256, 0, stream>>>(x, y, n2g + l * kD, n2b + l * kD);
    }

    pool_k<<<dim3(2, 8), 256, 0, stream>>>(x, partial);
    head_k<<<1, 256, 0, stream>>>(partial, c1w, c1b, c2w, c2b, (float*)d_out);
}

// Round 3
// 657.222 us; speedup vs baseline: 1.3862x; 1.0214x over previous
//
#include <hip/hip_runtime.h>

namespace {
constexpr int kS   = 1024;
constexpr int kD   = 512;
constexpr int kH   = 8;
constexpr int kDFF = 2048;
constexpr int kNF  = 85;   // D//6
constexpr int BK   = 16;
}

// ---------------- small reduction helpers ----------------
__device__ __forceinline__ float wave_sum(float v) {
#pragma unroll
    for (int o = 1; o < 64; o <<= 1) v += __shfl_xor(v, o, 64);
    return v;
}
__device__ __forceinline__ float wave_max(float v) {
#pragma unroll
    for (int o = 1; o < 64; o <<= 1) v = fmaxf(v, __shfl_xor(v, o, 64));
    return v;
}

// ---------------- input projection + positional encoding ----------------
__global__ __launch_bounds__(256)
void input_pe_k(const float* __restrict__ feat, const float* __restrict__ pos,
                const float* __restrict__ fb, const float* __restrict__ in_w,
                const float* __restrict__ in_b, float* __restrict__ x)
{
    int s = blockIdx.x;
    int t = threadIdx.x;
    __shared__ float f[64];
    if (t < 64) f[t] = feat[s * 64 + t];
    __syncthreads();
    float acc0 = in_b[t], acc1 = in_b[t + 256];
#pragma unroll 8
    for (int c = 0; c < 64; ++c) {
        float fv = f[c];
        acc0 = fmaf(fv, in_w[c * kD + t], acc0);
        acc1 = fmaf(fv, in_w[c * kD + 256 + t], acc1);
    }
    float pe0 = 0.f, pe1 = 0.f;
    {
        int d = t;
        if (d < 6 * kNF) {
            int seg = d / kNF, idx = d - seg * kNF;
            float cs = pos[s * 3 + (seg >> 1)] * fb[idx];
            pe0 = (seg & 1) ? cosf(cs) : sinf(cs);
        }
        d = t + 256;
        if (d < 6 * kNF) {
            int seg = d / kNF, idx = d - seg * kNF;
            float cs = pos[s * 3 + (seg >> 1)] * fb[idx];
            pe1 = (seg & 1) ? cosf(cs) : sinf(cs);
        }
    }
    x[s * kD + t]       = acc0 + pe0;
    x[s * kD + 256 + t] = acc1 + pe1;
}

// ---------------- pairwise distance matrix ----------------
__global__ __launch_bounds__(256)
void dist_k(const float* __restrict__ pos, float* __restrict__ dist)
{
    int i = blockIdx.x;
    float px = pos[i * 3], py = pos[i * 3 + 1], pz = pos[i * 3 + 2];
    for (int j = threadIdx.x; j < kS; j += 256) {
        float dx = px - pos[j * 3], dy = py - pos[j * 3 + 1], dz = pz - pos[j * 3 + 2];
        float sq = dx * dx + dy * dy + dz * dz;
        dist[(long)i * kS + j] = sq > 0.f ? sqrtf(sq) : 0.f;
    }
}

// ---------------- exact PWL factorization of the distance-bias MLP ----------------
// All inputs staged to LDS (the round-2 version serialized global w2 loads: 57us).
// grid.x = layer.
__global__ __launch_bounds__(256)
void pwl_build_k(const float* __restrict__ a_, const float* __restrict__ b_,
                 const float* __restrict__ w2, const float* __restrict__ b2,
                 float* __restrict__ bp_out, float* __restrict__ Atab, float* __restrict__ Btab)
{
    int l = blockIdx.x;
    a_ += l * 128; b_ += l * 128; w2 += l * 1024; b2 += l * 8;
    bp_out += l * 128; Atab += l * 1040; Btab += l * 1040;

    __shared__ float key[128], av[128], bv[128], sw2[1024], sb2[8];
    int t = threadIdx.x;
    for (int i = t; i < 1024; i += 256) sw2[i] = w2[i];
    if (t < 8) sb2[t] = b2[t];
    if (t < 128) {
        float a = a_[t], b = b_[t];
        av[t] = a; bv[t] = b;
        key[t] = (a != 0.f) ? (-b / a) : 3.0e38f;
    }
    __syncthreads();
    for (int ksz = 2; ksz <= 128; ksz <<= 1) {
        for (int j = ksz >> 1; j > 0; j >>= 1) {
            if (t < 128) {
                int ixj = t ^ j;
                if (ixj > t) {
                    bool up = ((t & ksz) == 0);
                    float x0 = key[t], x1 = key[ixj];
                    if ((x0 > x1) == up) { key[t] = x1; key[ixj] = x0; }
                }
            }
            __syncthreads();
        }
    }
    if (t < 128) bp_out[t] = key[t];
    __syncthreads();
    for (int task = t; task < 129 * 8; task += 256) {
        int seg = task >> 3, h = task & 7;
        float m;
        if (seg == 0)        m = key[0] - 1.0f;
        else if (seg == 128) m = key[127] + 1.0f;
        else                 m = 0.5f * (key[seg - 1] + key[seg]);
        float A = 0.f, B = 0.f;
        for (int c = 0; c < 128; ++c) {
            float a = av[c], b = bv[c];
            if (fmaf(a, m, b) > 0.f) {
                float w = sw2[c * 8 + h];
                A = fmaf(a, w, A);
                B = fmaf(b, w, B);
            }
        }
        Atab[seg * 8 + h] = A;
        Btab[seg * 8 + h] = B + sb2[h];
    }
}

// ---------------- fp32 tiled GEMM: 128xBN_ tile, 8x(BN_/16) microtile ----------
// SPLIT==0: C[z] = A[z]@B[z], EPI (0: +bias, 2: *scale + PWL-bias(dist,head=z))
// SPLIT==1: K = K-per-slice, blockIdx.z = z*splitk+ks, partial -> Cpart[bz][M][N]
template <int BN_, int TRANSB, int EPI, int SPLIT>
__global__ __launch_bounds__(256, 2)
void gemm_k(const float* __restrict__ A,
            const float* __restrict__ B0, const float* __restrict__ B1, const float* __restrict__ B2,
            const float* __restrict__ bias0, const float* __restrict__ bias1, const float* __restrict__ bias2,
            float* __restrict__ C0, float* __restrict__ C1, float* __restrict__ C2,
            int M, int N, int K, int lda, int ldb, int ldc,
            long sA, long sB, long sC, int splitk,
            const float* __restrict__ dist, const float* __restrict__ bp,
            const float* __restrict__ Atab, const float* __restrict__ Btab, float scale,
            float* __restrict__ Cpart)
{
    constexpr int BM_ = 128;
    constexpr int JW  = BN_ / 16;          // cols per thread (8 or 4)
    int bz = blockIdx.z;
    int z  = SPLIT ? bz / splitk : bz;
    int ks = SPLIT ? bz - z * splitk : 0;

    const float* Ap = A + (long)z * sA + (SPLIT ? (long)ks * K : 0);
    const float* Bb = ((z == 1) ? B1 : (z == 2) ? B2 : B0) + (long)z * sB;
    const float* Bp = Bb + (SPLIT ? (TRANSB ? (long)ks * K : (long)ks * K * ldb) : 0);

    __shared__ float As[BK][BM_ + 4];
    __shared__ float Bs[BK][BN_ + 4];
    __shared__ float bps[128];

    int tid = threadIdx.x;
    if (EPI == 2 && tid < 128) bps[tid] = bp[tid];

    int bm = blockIdx.x * BM_;
    int bn = blockIdx.y * BN_;
    int tx = tid & 15;
    int ty = tid >> 4;

    // ---- loader lane mapping ----
    int am  = tid >> 1;            // A row in tile (0..127)
    int akq = (tid & 1) << 3;      // A k offset (0 or 8)
    // B non-trans
    int bnb128 = (tid & 31) << 2;  // BN=128: n offset
    int bkb128 = tid >> 5;         // BN=128: k row (0..7), +8 for second
    int bnb64  = (tid & 15) << 2;  // BN=64
    int bkb64  = tid >> 4;         // BN=64: k row (0..15)
    // B trans (BN=128 only)
    int btn = tid >> 1;            // B row (= n) 0..127
    int btk = (tid & 1) << 3;      // k offset

    float acc[8][JW] = {};
    float4 aR0, aR1, bR0, bR1;

    auto ldA = [&](int k0) {
        const float* p = Ap + (long)(bm + am) * lda + k0 + akq;
        aR0 = *reinterpret_cast<const float4*>(p);
        aR1 = *reinterpret_cast<const float4*>(p + 4);
    };
    auto ldB = [&](int k0) {
        if constexpr (TRANSB) {
            const float* p = Bp + (long)(bn + btn) * ldb + k0 + btk;
            bR0 = *reinterpret_cast<const float4*>(p);
            bR1 = *reinterpret_cast<const float4*>(p + 4);
        } else if constexpr (BN_ == 128) {
            bR0 = *reinterpret_cast<const float4*>(Bp + (long)(k0 + bkb128) * ldb + bn + bnb128);
            bR1 = *reinterpret_cast<const float4*>(Bp + (long)(k0 + bkb128 + 8) * ldb + bn + bnb128);
        } else {
            bR0 = *reinterpret_cast<const float4*>(Bp + (long)(k0 + bkb64) * ldb + bn + bnb64);
        }
    };

    ldA(0); ldB(0);

    for (int k0 = 0; k0 < K; k0 += BK) {
        // store staged regs to LDS (A transposed: As[k][m])
        As[akq + 0][am] = aR0.x; As[akq + 1][am] = aR0.y;
        As[akq + 2][am] = aR0.z; As[akq + 3][am] = aR0.w;
        As[akq + 4][am] = aR1.x; As[akq + 5][am] = aR1.y;
        As[akq + 6][am] = aR1.z; As[akq + 7][am] = aR1.w;
        if constexpr (TRANSB) {
            Bs[btk + 0][btn] = bR0.x; Bs[btk + 1][btn] = bR0.y;
            Bs[btk + 2][btn] = bR0.z; Bs[btk + 3][btn] = bR0.w;
            Bs[btk + 4][btn] = bR1.x; Bs[btk + 5][btn] = bR1.y;
            Bs[btk + 6][btn] = bR1.z; Bs[btk + 7][btn] = bR1.w;
        } else if constexpr (BN_ == 128) {
            *reinterpret_cast<float4*>(&Bs[bkb128][bnb128])     = bR0;
            *reinterpret_cast<float4*>(&Bs[bkb128 + 8][bnb128]) = bR1;
        } else {
            *reinterpret_cast<float4*>(&Bs[bkb64][bnb64]) = bR0;
        }
        __syncthreads();
        if (k0 + BK < K) { ldA(k0 + BK); ldB(k0 + BK); }   // overlap with compute
#pragma unroll
        for (int kk = 0; kk < BK; ++kk) {
            float4 a0 = *reinterpret_cast<const float4*>(&As[kk][ty * 8]);
            float4 a1 = *reinterpret_cast<const float4*>(&As[kk][ty * 8 + 4]);
            float a[8] = {a0.x, a0.y, a0.z, a0.w, a1.x, a1.y, a1.z, a1.w};
            float b[JW];
            if constexpr (BN_ == 128) {
                float4 b0 = *reinterpret_cast<const float4*>(&Bs[kk][tx * 8]);
                float4 b1 = *reinterpret_cast<const float4*>(&Bs[kk][tx * 8 + 4]);
                b[0] = b0.x; b[1] = b0.y; b[2] = b0.z; b[3] = b0.w;
                b[4] = b1.x; b[5] = b1.y; b[6] = b1.z; b[7] = b1.w;
            } else {
                float4 b0 = *reinterpret_cast<const float4*>(&Bs[kk][tx * 4]);
                b[0] = b0.x; b[1] = b0.y; b[2] = b0.z; b[3] = b0.w;
            }
#pragma unroll
            for (int i = 0; i < 8; ++i)
#pragma unroll
                for (int j = 0; j < JW; ++j)
                    acc[i][j] = fmaf(a[i], b[j], acc[i][j]);
        }
        __syncthreads();
    }

    int cn = bn + tx * JW;
    if constexpr (SPLIT) {
        float* Cp = Cpart + (long)bz * M * N;
#pragma unroll
        for (int i = 0; i < 8; ++i) {
            long row = (long)(bm + ty * 8 + i) * N + cn;
            *reinterpret_cast<float4*>(&Cp[row]) =
                make_float4(acc[i][0], acc[i][1], acc[i][2], acc[i][3]);
            if constexpr (JW == 8)
                *reinterpret_cast<float4*>(&Cp[row + 4]) =
                    make_float4(acc[i][4], acc[i][5], acc[i][6], acc[i][7]);
        }
    } else {
        const float* biasp = (z == 1) ? bias1 : (z == 2) ? bias2 : bias0;
        float* Cp = ((z == 1) ? C1 : (z == 2) ? C2 : C0) + (long)z * sC;
#pragma unroll
        for (int i = 0; i < 8; ++i) {
            int m = bm + ty * 8 + i;
            float vals[JW];
            if constexpr (EPI == 2) {
                float dv[8];
                float4 d0 = *reinterpret_cast<const float4*>(&dist[(long)m * kS + cn]);
                float4 d1 = *reinterpret_cast<const float4*>(&dist[(long)m * kS + cn + 4]);
                dv[0] = d0.x; dv[1] = d0.y; dv[2] = d0.z; dv[3] = d0.w;
                dv[4] = d1.x; dv[5] = d1.y; dv[6] = d1.z; dv[7] = d1.w;
#pragma unroll
                for (int j = 0; j < JW; ++j) {
                    float tval = dv[j];
                    int lo = 0, hi = 128;
                    while (lo < hi) { int mid = (lo + hi) >> 1; if (bps[mid] < tval) lo = mid + 1; else hi = mid; }
                    vals[j] = fmaf(acc[i][j], scale, fmaf(Atab[lo * 8 + z], tval, Btab[lo * 8 + z]));
                }
            } else {
#pragma unroll
                for (int j = 0; j < JW; ++j) {
                    float v = acc[i][j];
                    if (biasp) v += biasp[cn + j];
                    vals[j] = v;
                }
            }
            long row = (long)m * ldc + cn;
            *reinterpret_cast<float4*>(&Cp[row]) = make_float4(vals[0], vals[1], vals[2], vals[3]);
            if constexpr (JW == 8)
                *reinterpret_cast<float4*>(&Cp[row + 4]) = make_float4(vals[4], vals[5], vals[6], vals[7]);
        }
    }
}

// ---------------- split-K reduction: sum slices + bias (+relu) ----------------
template <int RELU>
__global__ __launch_bounds__(256)
void reduce_k(const float* __restrict__ part,
              float* __restrict__ C0, float* __restrict__ C1, float* __restrict__ C2,
              const float* __restrict__ bias0, const float* __restrict__ bias1, const float* __restrict__ bias2,
              int M, int N, int splitk, long sC, int ldc)
{
    int z = blockIdx.y;
    long MN = (long)M * N;
    long idx = ((long)blockIdx.x * 256 + threadIdx.x) * 4;
    if (idx >= MN) return;
    const float* pz = part + (long)z * splitk * MN + idx;
    float4 s = *reinterpret_cast<const float4*>(pz);
    for (int t = 1; t < splitk; ++t) {
        float4 v = *reinterpret_cast<const float4*>(pz + (long)t * MN);
        s.x += v.x; s.y += v.y; s.z += v.z; s.w += v.w;
    }
    int m = (int)(idx / N), n = (int)(idx - (long)m * N);
    const float* bzp = (z == 1) ? bias1 : (z == 2) ? bias2 : bias0;
    if (bzp) { s.x += bzp[n]; s.y += bzp[n + 1]; s.z += bzp[n + 2]; s.w += bzp[n + 3]; }
    if (RELU) {
        s.x = fmaxf(s.x, 0.f); s.y = fmaxf(s.y, 0.f);
        s.z = fmaxf(s.z, 0.f); s.w = fmaxf(s.w, 0.f);
    }
    float* Cp = ((z == 1) ? C1 : (z == 2) ? C2 : C0) + (long)z * sC;
    *reinterpret_cast<float4*>(&Cp[(long)m * ldc + n]) = s;
}

// ---------------- row softmax over 1024 columns (in place) ----------------
__global__ __launch_bounds__(256)
void softmax_k(float* __restrict__ p)
{
    __shared__ float sm[4];
    long row = blockIdx.x;
    float4* r = reinterpret_cast<float4*>(p + row * (long)kS);
    int t = threadIdx.x;
    float4 v = r[t];
    float m = fmaxf(fmaxf(v.x, v.y), fmaxf(v.z, v.w));
    m = wave_max(m);
    if ((t & 63) == 0) sm[t >> 6] = m;
    __syncthreads();
    m = fmaxf(fmaxf(sm[0], sm[1]), fmaxf(sm[2], sm[3]));
    float e0 = __expf(v.x - m), e1 = __expf(v.y - m), e2 = __expf(v.z - m), e3 = __expf(v.w - m);
    float s = e0 + e1 + e2 + e3;
    __syncthreads();
    s = wave_sum(s);
    if ((t & 63) == 0) sm[t >> 6] = s;
    __syncthreads();
    s = sm[0] + sm[1] + sm[2] + sm[3];
    float inv = 1.0f / s;
    r[t] = make_float4(e0 * inv, e1 * inv, e2 * inv, e3 * inv);
}

// ---------------- residual add + layernorm (in place on x) ----------------
__global__ __launch_bounds__(256)
void add_ln_k(float* __restrict__ x, const float* __restrict__ y,
              const float* __restrict__ g, const float* __restrict__ b)
{
    __shared__ float sm[4];
    int row = blockIdx.x, t = threadIdx.x;
    float* xr = x + (long)row * kD;
    const float* yr = y + (long)row * kD;
    float s0 = xr[t] + yr[t];
    float s1 = xr[t + 256] + yr[t + 256];
    float sum = wave_sum(s0 + s1);
    if ((t & 63) == 0) sm[t >> 6] = sum;
    __syncthreads();
    sum = sm[0] + sm[1] + sm[2] + sm[3];
    float mu = sum * (1.f / kD);
    float d0 = s0 - mu, d1 = s1 - mu;
    __syncthreads();
    float vs = wave_sum(d0 * d0 + d1 * d1);
    if ((t & 63) == 0) sm[t >> 6] = vs;
    __syncthreads();
    vs = sm[0] + sm[1] + sm[2] + sm[3];
    float rs = rsqrtf(vs * (1.f / kD) + 1e-5f);
    xr[t]       = fmaf(d0 * rs, g[t], b[t]);
    xr[t + 256] = fmaf(d1 * rs, g[t + 256], b[t + 256]);
}

// ---------------- mean-pool partials ----------------
__global__ __launch_bounds__(256)
void pool_k(const float* __restrict__ x, float* __restrict__ partial)
{
    int col = blockIdx.x * 256 + threadIdx.x;
    int rb = blockIdx.y;
    float s = 0.f;
    for (int r = rb * 128; r < rb * 128 + 128; ++r) s += x[(long)r * kD + col];
    partial[rb * kD + col] = s;
}

// ---------------- classifier head ----------------
__global__ __launch_bounds__(256)
void head_k(const float* __restrict__ partial,
            const float* __restrict__ c1w, const float* __restrict__ c1b,
            const float* __restrict__ c2w, const float* __restrict__ c2b,
            float* __restrict__ out)
{
    __shared__ float pooled[kD];
    __shared__ float h1[256];
    int t = threadIdx.x;
    for (int d = t; d < kD; d += 256) {
        float s = 0.f;
        for (int r = 0; r < 8; ++r) s += partial[r * kD + d];
        pooled[d] = s * (1.0f / kS);
    }
    __syncthreads();
    float acc = c1b[t];
    for (int f = 0; f < kD; ++f) acc = fmaf(pooled[f], c1w[f * 256 + t], acc);
    h1[t] = fmaxf(acc, 0.f);
    __syncthreads();
    if (t < 10) {
        float o = c2b[t];
        for (int f = 0; f < 256; ++f) o = fmaf(h1[f], c2w[f * 10 + t], o);
        out[t] = o;
    }
}

// ---------------- launch ----------------
extern "C" void kernel_launch(void* const* d_in, const int* in_sizes, int n_in,
                              void* d_out, int out_size, void* d_ws, size_t ws_size,
                              hipStream_t stream)
{
    (void)in_sizes; (void)n_in; (void)out_size; (void)ws_size;
    const float* features = (const float*)d_in[0];
    const float* positions= (const float*)d_in[1];
    const float* fb       = (const float*)d_in[2];
    const float* in_w     = (const float*)d_in[3];
    const float* in_b     = (const float*)d_in[4];
    const float* qw  = (const float*)d_in[5];
    const float* qb  = (const float*)d_in[6];
    const float* kw  = (const float*)d_in[7];
    const float* kb  = (const float*)d_in[8];
    const float* vw  = (const float*)d_in[9];
    const float* vb  = (const float*)d_in[10];
    const float* ow  = (const float*)d_in[11];
    const float* ob  = (const float*)d_in[12];
    const float* db1w= (const float*)d_in[13];
    const float* db1b= (const float*)d_in[14];
    const float* db2w= (const float*)d_in[15];
    const float* db2b= (const float*)d_in[16];
    const float* n1g = (const float*)d_in[17];
    const float* n1b = (const float*)d_in[18];
    const float* n2g = (const float*)d_in[19];
    const float* n2b = (const float*)d_in[20];
    const float* f1w = (const float*)d_in[21];
    const float* f1b = (const float*)d_in[22];
    const float* f2w = (const float*)d_in[23];
    const float* f2b = (const float*)d_in[24];
    const float* c1w = (const float*)d_in[25];
    const float* c1b = (const float*)d_in[26];
    const float* c2w = (const float*)d_in[27];
    const float* c2b = (const float*)d_in[28];

    float* ws = (float*)d_ws;
    const long SD = (long)kS * kD;           // 524288
    float* x      = ws;
    float* q      = ws + 1 * SD;
    float* kbuf   = ws + 2 * SD;
    float* v      = ws + 3 * SD;
    float* ao     = ws + 4 * SD;
    float* y      = ws + 5 * SD;
    float* hbuf   = ws + 6 * SD;             // S*DFF = 2097152 floats (8 MB)
    float* dist   = hbuf + (long)kS * kDFF;
    float* scores = dist + (long)kS * kS;    // 8*1024*1024 floats (32 MB)
    float* bpw    = scores + (long)kH * kS * kS;  // [2][128]
    float* Atab   = bpw + 2 * 128;                // [2][1040]
    float* Btab   = Atab + 2 * 1040;
    float* partial= Btab + 2 * 1040;

    // partial overlays (regions dead at time of use)
    float* part_big = scores;   // QKV/O-proj/FFN1/FFN2 partials (scores not live)
    float* part_av  = hbuf;     // AV partials (hbuf not live), 32*65536 = 2.1M floats

    input_pe_k<<<kS, 256, 0, stream>>>(features, positions, fb, in_w, in_b, x);
    dist_k<<<kS, 256, 0, stream>>>(positions, dist);
    pwl_build_k<<<2, 256, 0, stream>>>(db1w, db1b, db2w, db2b, bpw, Atab, Btab);

    const long SS = (long)kS * kS;
    for (int l = 0; l < 2; ++l) {
        const float* qwl = qw + (long)l * kD * kD;
        const float* kwl = kw + (long)l * kD * kD;
        const float* vwl = vw + (long)l * kD * kD;
        const float* owl = ow + (long)l * kD * kD;

        // fused QKV, split-K x4: grid.z = 3*4
        gemm_k<64, 0, 0, 1><<<dim3(8, 8, 12), 256, 0, stream>>>(
            x, qwl, kwl, vwl, nullptr, nullptr, nullptr,
            q, kbuf, v, kS, kD, 128, kD, kD, kD, 0, 0, 0, 4,
            nullptr, nullptr, nullptr, nullptr, 0.f, part_big);
        reduce_k<0><<<dim3(512, 3), 256, 0, stream>>>(
            part_big, q, kbuf, v, qb + l * kD, kb + l * kD, vb + l * kD,
            kS, kD, 4, 0, kD);

        // scores = (q @ k^T)*scale + PWL-bias, batched over heads
        gemm_k<128, 1, 2, 0><<<dim3(8, 8, 8), 256, 0, stream>>>(
            q, kbuf, kbuf, kbuf, nullptr, nullptr, nullptr,
            scores, scores, scores, kS, kS, 64, kD, kD, kS, 64, 64, SS, 1,
            dist, bpw + l * 128, Atab + l * 1040, Btab + l * 1040, 0.125f, nullptr);
        softmax_k<<<kH * kS, 256, 0, stream>>>(scores);

        // attn @ v, split-K x4 per head
        gemm_k<64, 0, 0, 1><<<dim3(8, 1, 32), 256, 0, stream>>>(
            scores, v, v, v, nullptr, nullptr, nullptr,
            ao, ao, ao, kS, 64, 256, kS, kD, kD, SS, 64, 64, 4,
            nullptr, nullptr, nullptr, nullptr, 0.f, part_av);
        reduce_k<0><<<dim3(64, 8), 256, 0, stream>>>(
            part_av, ao, ao, ao, nullptr, nullptr, nullptr,
            kS, 64, 4, 64, kD);

        // output projection, split-K x8
        gemm_k<64, 0, 0, 1><<<dim3(8, 8, 8), 256, 0, stream>>>(
            ao, owl, owl, owl, nullptr, nullptr, nullptr,
            y, y, y, kS, kD, 64, kD, kD, kD, 0, 0, 0, 8,
            nullptr, nullptr, nullptr, nullptr, 0.f, part_big);
        reduce_k<0><<<dim3(512, 1), 256, 0, stream>>>(
            part_big, y, y, y, ob + l * kD, ob + l * kD, ob + l * kD,
            kS, kD, 8, 0, kD);

        add_ln_k<<<kS, 256, 0, stream>>>(x, y, n1g + l * kD, n1b + l * kD);

        // FFN1, split-K x4 (relu in reduce)
        const float* f1wl = f1w + (long)l * kD * kDFF;
        const float* f2wl = f2w + (long)l * kDFF * kD;
        gemm_k<128, 0, 0, 1><<<dim3(8, 16, 4), 256, 0, stream>>>(
            x, f1wl, f1wl, f1wl, nullptr, nullptr, nullptr,
            hbuf, hbuf, hbuf, kS, kDFF, 128, kD, kDFF, kDFF, 0, 0, 0, 4,
            nullptr, nullptr, nullptr, nullptr, 0.f, part_big);
        reduce_k<1><<<dim3(2048, 1), 256, 0, stream>>>(
            part_big, hbuf, hbuf, hbuf, f1b + l * kDFF, f1b + l * kDFF, f1b + l * kDFF,
            kS, kDFF, 4, 0, kDFF);

        // FFN2, split-K x8
        gemm_k<64, 0, 0, 1><<<dim3(8, 8, 8), 256, 0, stream>>>(
            hbuf, f2wl, f2wl, f2wl, nullptr, nullptr, nullptr,
            y, y, y, kS, kD, 256, kDFF, kD, kD, 0, 0, 0, 8,
            nullptr, nullptr, nullptr, nullptr, 0.f, part_big);
        reduce_k<0><<<dim3(512, 1), 256, 0, stream>>>(
            part_big, y, y, y, f2b + l * kD, f2b + l * kD, f2b + l * kD,
            kS, kD, 8, 0, kD);

        add_ln_k<<<kS, 256, 0, stream>>>(x, y, n2g + l * kD, n2b + l * kD);
    }

    pool_k<<<dim3(2, 8), 256, 0, stream>>>(x, partial);
    head_k<<<1, 256, 0, stream>>>(partial, c1w, c1b, c2w, c2b, (float*)d_out);
}

// Round 5
// 615.004 us; speedup vs baseline: 1.4814x; 1.0686x over previous
//
#include <hip/hip_runtime.h>

namespace {
constexpr int kS   = 1024;
constexpr int kD   = 512;
constexpr int kH   = 8;
constexpr int kDFF = 2048;
constexpr int kNF  = 85;   // D//6
}

typedef __attribute__((ext_vector_type(8))) short bhalf8_t;    // 8x16-bit in 4 VGPRs
typedef _Float16 half8_t __attribute__((ext_vector_type(8)));
typedef __attribute__((ext_vector_type(4))) float f32x4_t;

// ---------------- helpers ----------------
__device__ __forceinline__ float wave_sum(float v) {
#pragma unroll
    for (int o = 1; o < 64; o <<= 1) v += __shfl_xor(v, o, 64);
    return v;
}
__device__ __forceinline__ float wave_max(float v) {
#pragma unroll
    for (int o = 1; o < 64; o <<= 1) v = fmaxf(v, __shfl_xor(v, o, 64));
    return v;
}
__device__ __forceinline__ unsigned short f2bf(float f) {   // RNE fp32->bf16
    unsigned u = __float_as_uint(f);
    u = (u + 0x7FFF + ((u >> 16) & 1)) >> 16;
    return (unsigned short)u;
}
__device__ __forceinline__ float bf2f(unsigned short h) {
    return __uint_as_float(((unsigned)h) << 16);
}
__device__ __forceinline__ unsigned short f2h(float f) {    // RNE fp32->fp16
    _Float16 h = (_Float16)f;
    return __builtin_bit_cast(unsigned short, h);
}

// ---------------- input projection + positional encoding ----------------
__global__ __launch_bounds__(256)
void input_pe_k(const float* __restrict__ feat, const float* __restrict__ pos,
                const float* __restrict__ fb, const float* __restrict__ in_w,
                const float* __restrict__ in_b, float* __restrict__ x)
{
    int s = blockIdx.x;
    int t = threadIdx.x;
    __shared__ float f[64];
    if (t < 64) f[t] = feat[s * 64 + t];
    __syncthreads();
    float acc0 = in_b[t], acc1 = in_b[t + 256];
#pragma unroll 8
    for (int c = 0; c < 64; ++c) {
        float fv = f[c];
        acc0 = fmaf(fv, in_w[c * kD + t], acc0);
        acc1 = fmaf(fv, in_w[c * kD + 256 + t], acc1);
    }
    float pe0 = 0.f, pe1 = 0.f;
    {
        int d = t;
        if (d < 6 * kNF) {
            int seg = d / kNF, idx = d - seg * kNF;
            float cs = pos[s * 3 + (seg >> 1)] * fb[idx];
            pe0 = (seg & 1) ? cosf(cs) : sinf(cs);
        }
        d = t + 256;
        if (d < 6 * kNF) {
            int seg = d / kNF, idx = d - seg * kNF;
            float cs = pos[s * 3 + (seg >> 1)] * fb[idx];
            pe1 = (seg & 1) ? cosf(cs) : sinf(cs);
        }
    }
    x[s * kD + t]       = acc0 + pe0;
    x[s * kD + 256 + t] = acc1 + pe1;
}

// ---------------- pairwise distance matrix ----------------
__global__ __launch_bounds__(256)
void dist_k(const float* __restrict__ pos, float* __restrict__ dist)
{
    int i = blockIdx.x;
    float px = pos[i * 3], py = pos[i * 3 + 1], pz = pos[i * 3 + 2];
    for (int j = threadIdx.x; j < kS; j += 256) {
        float dx = px - pos[j * 3], dy = py - pos[j * 3 + 1], dz = pz - pos[j * 3 + 2];
        float sq = dx * dx + dy * dy + dz * dz;
        dist[(long)i * kS + j] = sq > 0.f ? sqrtf(sq) : 0.f;
    }
}

// ---------------- exact PWL factorization of the distance-bias MLP ----------------
__global__ __launch_bounds__(256)
void pwl_build_k(const float* __restrict__ a_, const float* __restrict__ b_,
                 const float* __restrict__ w2, const float* __restrict__ b2,
                 float* __restrict__ bp_out, float* __restrict__ Atab, float* __restrict__ Btab)
{
    int l = blockIdx.x;
    a_ += l * 128; b_ += l * 128; w2 += l * 1024; b2 += l * 8;
    bp_out += l * 128; Atab += l * 1040; Btab += l * 1040;

    __shared__ float key[128], av[128], bv[128], sw2[1024], sb2[8];
    int t = threadIdx.x;
    for (int i = t; i < 1024; i += 256) sw2[i] = w2[i];
    if (t < 8) sb2[t] = b2[t];
    if (t < 128) {
        float a = a_[t], b = b_[t];
        av[t] = a; bv[t] = b;
        key[t] = (a != 0.f) ? (-b / a) : 3.0e38f;
    }
    __syncthreads();
    for (int ksz = 2; ksz <= 128; ksz <<= 1) {
        for (int j = ksz >> 1; j > 0; j >>= 1) {
            if (t < 128) {
                int ixj = t ^ j;
                if (ixj > t) {
                    bool up = ((t & ksz) == 0);
                    float x0 = key[t], x1 = key[ixj];
                    if ((x0 > x1) == up) { key[t] = x1; key[ixj] = x0; }
                }
            }
            __syncthreads();
        }
    }
    if (t < 128) bp_out[t] = key[t];
    __syncthreads();
    for (int task = t; task < 129 * 8; task += 256) {
        int seg = task >> 3, h = task & 7;
        float m;
        if (seg == 0)        m = key[0] - 1.0f;
        else if (seg == 128) m = key[127] + 1.0f;
        else                 m = 0.5f * (key[seg - 1] + key[seg]);
        float A = 0.f, B = 0.f;
        for (int c = 0; c < 128; ++c) {
            float a = av[c], b = bv[c];
            if (fmaf(a, m, b) > 0.f) {
                float w = sw2[c * 8 + h];
                A = fmaf(a, w, A);
                B = fmaf(b, w, B);
            }
        }
        Atab[seg * 8 + h] = A;
        Btab[seg * 8 + h] = B + sb2[h];
    }
}

// ---------------- fp32 -> bf16 3-term split, row-major ----------------
// order 0 (A-side): [hi | lo | hi].  order 1 (B-side): [hi | hi | lo].
// Pairing A(order0) with B(order1) along 3K gives hi*hi + lo*hi + hi*lo.
__global__ __launch_bounds__(256)
void split3_rm_k(const float* __restrict__ in, unsigned short* __restrict__ out,
                 int total, int kshift, int ldin, long szIn, long szOut, int order)
{
    int z = blockIdx.y;
    long i = ((long)blockIdx.x * 256 + threadIdx.x) * 4;
    if (i >= total) return;
    int K = 1 << kshift;
    int m = (int)(i >> kshift), k = (int)(i & (K - 1));
    const float* ip = in + (long)z * szIn + (long)m * ldin + k;
    float4 v = *reinterpret_cast<const float4*>(ip);
    unsigned short h[4], lo[4];
    float fv[4] = {v.x, v.y, v.z, v.w};
#pragma unroll
    for (int j = 0; j < 4; ++j) {
        h[j] = f2bf(fv[j]);
        lo[j] = f2bf(fv[j] - bf2f(h[j]));
    }
    unsigned short* op = out + (long)z * szOut + (long)m * (3 * K) + k;
    ushort4 hv = make_ushort4(h[0], h[1], h[2], h[3]);
    ushort4 lv = make_ushort4(lo[0], lo[1], lo[2], lo[3]);
    *reinterpret_cast<ushort4*>(op) = hv;
    if (order == 0) {
        *reinterpret_cast<ushort4*>(op + K)     = lv;
        *reinterpret_cast<ushort4*>(op + 2 * K) = hv;
    } else {
        *reinterpret_cast<ushort4*>(op + K)     = hv;
        *reinterpret_cast<ushort4*>(op + 2 * K) = lv;
    }
}

// ---------------- fp32 K x N -> bf16 N x 3K transpose-split (weights, B-side) ----
// B-side order: [hi | hi | lo]
__global__ __launch_bounds__(256)
void split3_tr_k(const float* __restrict__ in, unsigned short* __restrict__ out,
                 int K, int N, long szIn, long szOut)
{
    __shared__ float tile[32][33];
    int z = blockIdx.z;
    in  += (long)z * szIn;
    out += (long)z * szOut;
    int k0 = blockIdx.x * 32, n0 = blockIdx.y * 32;
    int t = threadIdx.x;
    int r = t >> 3, c4 = (t & 7) * 4;
    float4 v = *reinterpret_cast<const float4*>(&in[(long)(k0 + r) * N + n0 + c4]);
    tile[r][c4] = v.x; tile[r][c4 + 1] = v.y; tile[r][c4 + 2] = v.z; tile[r][c4 + 3] = v.w;
    __syncthreads();
    int nr = t >> 3, kq = (t & 7) * 4;
    unsigned short h[4], lo[4];
#pragma unroll
    for (int j = 0; j < 4; ++j) {
        float f = tile[kq + j][nr];
        h[j] = f2bf(f);
        lo[j] = f2bf(f - bf2f(h[j]));
    }
    unsigned short* op = out + (long)(n0 + nr) * (3 * K) + k0 + kq;
    ushort4 hv = make_ushort4(h[0], h[1], h[2], h[3]);
    *reinterpret_cast<ushort4*>(op)         = hv;
    *reinterpret_cast<ushort4*>(op + K)     = hv;
    *reinterpret_cast<ushort4*>(op + 2 * K) = make_ushort4(lo[0], lo[1], lo[2], lo[3]);
}

// ---------------- fp32 -> f16 with scale (P matrix) ----------------
__global__ __launch_bounds__(256)
void tof16_k(const float* __restrict__ in, unsigned short* __restrict__ out,
             long total, float scl)
{
    long i = ((long)blockIdx.x * 256 + threadIdx.x) * 4;
    if (i >= total) return;
    float4 v = *reinterpret_cast<const float4*>(in + i);
    *reinterpret_cast<ushort4*>(out + i) =
        make_ushort4(f2h(v.x * scl), f2h(v.y * scl), f2h(v.z * scl), f2h(v.w * scl));
}

// ---------------- fp32 K x N -> f16 N x K transpose with scale (V matrix) -------
__global__ __launch_bounds__(256)
void tr_f16_k(const float* __restrict__ in, unsigned short* __restrict__ out,
              int K, int N, float scl)
{
    __shared__ float tile[32][33];
    int k0 = blockIdx.x * 32, n0 = blockIdx.y * 32;
    int t = threadIdx.x;
    int r = t >> 3, c4 = (t & 7) * 4;
    float4 v = *reinterpret_cast<const float4*>(&in[(long)(k0 + r) * N + n0 + c4]);
    tile[r][c4] = v.x; tile[r][c4 + 1] = v.y; tile[r][c4 + 2] = v.z; tile[r][c4 + 3] = v.w;
    __syncthreads();
    int nr = t >> 3, kq = (t & 7) * 4;
    unsigned short h[4];
#pragma unroll
    for (int j = 0; j < 4; ++j) h[j] = f2h(tile[kq + j][nr] * scl);
    *reinterpret_cast<ushort4*>(&out[(long)(n0 + nr) * K + k0 + kq]) =
        make_ushort4(h[0], h[1], h[2], h[3]);
}

// ---------------- 16-bit MFMA GEMM (DT 0 = bf16, 1 = f16) ----------------
// A: M x K row-major (lda), B: N x K row-major (ldb) — B pre-transposed.
// Tile 128 x BN_, 4 waves. BN_=128: 2x2 waves of 64x64. BN_=64: 4x1 waves of 32x64.
// SPLIT: K = slice len, bz = z*splitk+ks, partial -> Cpart[bz][M][N].
// EPI 0: plain store C0 + z*sC. EPI 2: v*scale + PWL-bias(dist, head=z).
template <int BN_, int EPI, int SPLIT, int DT>
__global__ __launch_bounds__(256, 2)
void bgemm_k(const unsigned short* __restrict__ A,
             const unsigned short* __restrict__ B0, const unsigned short* __restrict__ B1,
             const unsigned short* __restrict__ B2,
             float* __restrict__ C0,
             int M, int N, int K, int lda, int ldb, int ldc,
             long sA, long sB, long sC, int splitk,
             const float* __restrict__ dist, const float* __restrict__ bp,
             const float* __restrict__ Atab, const float* __restrict__ Btab, float scale,
             float* __restrict__ Cpart)
{
    constexpr int BM_ = 128;
    constexpr int BKp = 40;                 // LDS row stride (80 B, 16B-aligned)
    constexpr int TM  = (BN_ == 128) ? 4 : 2;
    constexpr int TN  = 4;

    int tid = threadIdx.x;
    int bz = blockIdx.z;
    int z  = SPLIT ? bz / splitk : bz;
    int ks = SPLIT ? bz - z * splitk : 0;

    const unsigned short* Ap = A + (long)z * sA + (long)ks * K;
    const unsigned short* Bp = ((z == 1) ? B1 : (z == 2) ? B2 : B0) + (long)z * sB + (long)ks * K;

    __shared__ unsigned short As[BM_ * BKp];
    __shared__ unsigned short Bs[BN_ * BKp];
    __shared__ float bps[128];
    if (EPI == 2 && tid < 128) bps[tid] = bp[tid];

    int bm = blockIdx.x * BM_;
    int bn = blockIdx.y * BN_;
    int w = tid >> 6, lane = tid & 63, quad = lane >> 4, l16 = lane & 15;
    int wm = (BN_ == 128) ? (w >> 1) * 64 : w * 32;
    int wn = (BN_ == 128) ? (w & 1) * 64 : 0;

    int ar = tid >> 1, ac = (tid & 1) * 16;
    int br = (BN_ == 128) ? (tid >> 1) : (tid >> 2);
    int bc = (BN_ == 128) ? (tid & 1) * 16 : (tid & 3) * 8;

    f32x4_t acc[TM][TN] = {};
    bhalf8_t aS0, aS1, bS0, bS1;

    auto ldgA = [&](int k0) {
        const unsigned short* p = Ap + (long)(bm + ar) * lda + k0 + ac;
        aS0 = *reinterpret_cast<const bhalf8_t*>(p);
        aS1 = *reinterpret_cast<const bhalf8_t*>(p + 8);
    };
    auto ldgB = [&](int k0) {
        const unsigned short* p = Bp + (long)(bn + br) * ldb + k0 + bc;
        bS0 = *reinterpret_cast<const bhalf8_t*>(p);
        if (BN_ == 128) bS1 = *reinterpret_cast<const bhalf8_t*>(p + 8);
    };

    ldgA(0); ldgB(0);

    for (int k0 = 0; k0 < K; k0 += 32) {
        *reinterpret_cast<bhalf8_t*>(&As[ar * BKp + ac])     = aS0;
        *reinterpret_cast<bhalf8_t*>(&As[ar * BKp + ac + 8]) = aS1;
        *reinterpret_cast<bhalf8_t*>(&Bs[br * BKp + bc]) = bS0;
        if (BN_ == 128) *reinterpret_cast<bhalf8_t*>(&Bs[br * BKp + bc + 8]) = bS1;
        __syncthreads();
        if (k0 + 32 < K) { ldgA(k0 + 32); ldgB(k0 + 32); }
        bhalf8_t af[TM], bf[TN];
#pragma unroll
        for (int i = 0; i < TM; ++i)
            af[i] = *reinterpret_cast<const bhalf8_t*>(&As[(wm + i * 16 + l16) * BKp + quad * 8]);
#pragma unroll
        for (int j = 0; j < TN; ++j)
            bf[j] = *reinterpret_cast<const bhalf8_t*>(&Bs[(wn + j * 16 + l16) * BKp + quad * 8]);
#pragma unroll
        for (int i = 0; i < TM; ++i)
#pragma unroll
            for (int j = 0; j < TN; ++j) {
                if constexpr (DT == 0) {
                    acc[i][j] = __builtin_amdgcn_mfma_f32_16x16x32_bf16(af[i], bf[j], acc[i][j], 0, 0, 0);
                } else {
                    acc[i][j] = __builtin_amdgcn_mfma_f32_16x16x32_f16(
                        __builtin_bit_cast(half8_t, af[i]), __builtin_bit_cast(half8_t, bf[j]),
                        acc[i][j], 0, 0, 0);
                }
            }
        __syncthreads();
    }

    if constexpr (SPLIT) {
        float* Cp = Cpart + (long)bz * M * N;
#pragma unroll
        for (int i = 0; i < TM; ++i)
#pragma unroll
            for (int j = 0; j < TN; ++j)
#pragma unroll
                for (int r = 0; r < 4; ++r) {
                    int m = bm + wm + i * 16 + quad * 4 + r;
                    int n = bn + wn + j * 16 + l16;
                    Cp[(long)m * N + n] = acc[i][j][r];
                }
    } else {
        float* Cp = C0 + (long)z * sC;
#pragma unroll
        for (int i = 0; i < TM; ++i)
#pragma unroll
            for (int j = 0; j < TN; ++j)
#pragma unroll
                for (int r = 0; r < 4; ++r) {
                    int m = bm + wm + i * 16 + quad * 4 + r;
                    int n = bn + wn + j * 16 + l16;
                    float v = acc[i][j][r];
                    if (EPI == 2) {
                        float tval = dist[(long)m * kS + n];
                        int lo = 0, hi = 128;
                        while (lo < hi) { int mid = (lo + hi) >> 1; if (bps[mid] < tval) lo = mid + 1; else hi = mid; }
                        v = fmaf(v, scale, fmaf(Atab[lo * 8 + z], tval, Btab[lo * 8 + z]));
                    }
                    Cp[(long)m * ldc + n] = v;
                }
    }
}

// ---------------- split-K reduction: (sum slices)*scl + bias (+relu) ----------------
template <int RELU>
__global__ __launch_bounds__(256)
void reduce_k(const float* __restrict__ part,
              float* __restrict__ C0, float* __restrict__ C1, float* __restrict__ C2,
              const float* __restrict__ bias0, const float* __restrict__ bias1, const float* __restrict__ bias2,
              int M, int N, int splitk, long sC, int ldc, float scl)
{
    int z = blockIdx.y;
    long MN = (long)M * N;
    long idx = ((long)blockIdx.x * 256 + threadIdx.x) * 4;
    if (idx >= MN) return;
    const float* pz = part + (long)z * splitk * MN + idx;
    float4 s = *reinterpret_cast<const float4*>(pz);
    for (int t = 1; t < splitk; ++t) {
        float4 v = *reinterpret_cast<const float4*>(pz + (long)t * MN);
        s.x += v.x; s.y += v.y; s.z += v.z; s.w += v.w;
    }
    s.x *= scl; s.y *= scl; s.z *= scl; s.w *= scl;
    int m = (int)(idx / N), n = (int)(idx - (long)m * N);
    const float* bzp = (z == 1) ? bias1 : (z == 2) ? bias2 : bias0;
    if (bzp) { s.x += bzp[n]; s.y += bzp[n + 1]; s.z += bzp[n + 2]; s.w += bzp[n + 3]; }
    if (RELU) {
        s.x = fmaxf(s.x, 0.f); s.y = fmaxf(s.y, 0.f);
        s.z = fmaxf(s.z, 0.f); s.w = fmaxf(s.w, 0.f);
    }
    float* Cp = ((z == 1) ? C1 : (z == 2) ? C2 : C0) + (long)z * sC;
    *reinterpret_cast<float4*>(&Cp[(long)m * ldc + n]) = s;
}

// ---------------- row softmax over 1024 columns (in place) ----------------
__global__ __launch_bounds__(256)
void softmax_k(float* __restrict__ p)
{
    __shared__ float sm[4];
    long row = blockIdx.x;
    float4* r = reinterpret_cast<float4*>(p + row * (long)kS);
    int t = threadIdx.x;
    float4 v = r[t];
    float m = fmaxf(fmaxf(v.x, v.y), fmaxf(v.z, v.w));
    m = wave_max(m);
    if ((t & 63) == 0) sm[t >> 6] = m;
    __syncthreads();
    m = fmaxf(fmaxf(sm[0], sm[1]), fmaxf(sm[2], sm[3]));
    float e0 = __expf(v.x - m), e1 = __expf(v.y - m), e2 = __expf(v.z - m), e3 = __expf(v.w - m);
    float s = e0 + e1 + e2 + e3;
    __syncthreads();
    s = wave_sum(s);
    if ((t & 63) == 0) sm[t >> 6] = s;
    __syncthreads();
    s = sm[0] + sm[1] + sm[2] + sm[3];
    float inv = 1.0f / s;
    r[t] = make_float4(e0 * inv, e1 * inv, e2 * inv, e3 * inv);
}

// ---------------- residual add + layernorm (in place on x) ----------------
__global__ __launch_bounds__(256)
void add_ln_k(float* __restrict__ x, const float* __restrict__ y,
              const float* __restrict__ g, const float* __restrict__ b)
{
    __shared__ float sm[4];
    int row = blockIdx.x, t = threadIdx.x;
    float* xr = x + (long)row * kD;
    const float* yr = y + (long)row * kD;
    float s0 = xr[t] + yr[t];
    float s1 = xr[t + 256] + yr[t + 256];
    float sum = wave_sum(s0 + s1);
    if ((t & 63) == 0) sm[t >> 6] = sum;
    __syncthreads();
    sum = sm[0] + sm[1] + sm[2] + sm[3];
    float mu = sum * (1.f / kD);
    float d0 = s0 - mu, d1 = s1 - mu;
    __syncthreads();
    float vs = wave_sum(d0 * d0 + d1 * d1);
    if ((t & 63) == 0) sm[t >> 6] = vs;
    __syncthreads();
    vs = sm[0] + sm[1] + sm[2] + sm[3];
    float rs = rsqrtf(vs * (1.f / kD) + 1e-5f);
    xr[t]       = fmaf(d0 * rs, g[t], b[t]);
    xr[t + 256] = fmaf(d1 * rs, g[t + 256], b[t + 256]);
}

// ---------------- mean-pool partials ----------------
__global__ __launch_bounds__(256)
void pool_k(const float* __restrict__ x, float* __restrict__ partial)
{
    int col = blockIdx.x * 256 + threadIdx.x;
    int rb = blockIdx.y;
    float s = 0.f;
    for (int r = rb * 128; r < rb * 128 + 128; ++r) s += x[(long)r * kD + col];
    partial[rb * kD + col] = s;
}

// ---------------- classifier head ----------------
__global__ __launch_bounds__(256)
void head_k(const float* __restrict__ partial,
            const float* __restrict__ c1w, const float* __restrict__ c1b,
            const float* __restrict__ c2w, const float* __restrict__ c2b,
            float* __restrict__ out)
{
    __shared__ float pooled[kD];
    __shared__ float h1[256];
    int t = threadIdx.x;
    for (int d = t; d < kD; d += 256) {
        float s = 0.f;
        for (int r = 0; r < 8; ++r) s += partial[r * kD + d];
        pooled[d] = s * (1.0f / kS);
    }
    __syncthreads();
    float acc = c1b[t];
    for (int f = 0; f < kD; ++f) acc = fmaf(pooled[f], c1w[f * 256 + t], acc);
    h1[t] = fmaxf(acc, 0.f);
    __syncthreads();
    if (t < 10) {
        float o = c2b[t];
        for (int f = 0; f < 256; ++f) o = fmaf(h1[f], c2w[f * 10 + t], o);
        out[t] = o;
    }
}

// ---------------- launch ----------------
extern "C" void kernel_launch(void* const* d_in, const int* in_sizes, int n_in,
                              void* d_out, int out_size, void* d_ws, size_t ws_size,
                              hipStream_t stream)
{
    (void)in_sizes; (void)n_in; (void)out_size; (void)ws_size;
    const float* features = (const float*)d_in[0];
    const float* positions= (const float*)d_in[1];
    const float* fb       = (const float*)d_in[2];
    const float* in_w     = (const float*)d_in[3];
    const float* in_b     = (const float*)d_in[4];
    const float* qw  = (const float*)d_in[5];
    const float* qb  = (const float*)d_in[6];
    const float* kw  = (const float*)d_in[7];
    const float* kb  = (const float*)d_in[8];
    const float* vw  = (const float*)d_in[9];
    const float* vb  = (const float*)d_in[10];
    const float* ow  = (const float*)d_in[11];
    const float* ob  = (const float*)d_in[12];
    const float* db1w= (const float*)d_in[13];
    const float* db1b= (const float*)d_in[14];
    const float* db2w= (const float*)d_in[15];
    const float* db2b= (const float*)d_in[16];
    const float* n1g = (const float*)d_in[17];
    const float* n1b = (const float*)d_in[18];
    const float* n2g = (const float*)d_in[19];
    const float* n2b = (const float*)d_in[20];
    const float* f1w = (const float*)d_in[21];
    const float* f1b = (const float*)d_in[22];
    const float* f2w = (const float*)d_in[23];
    const float* f2b = (const float*)d_in[24];
    const float* c1w = (const float*)d_in[25];
    const float* c1b = (const float*)d_in[26];
    const float* c2w = (const float*)d_in[27];
    const float* c2b = (const float*)d_in[28];

    float* ws = (float*)d_ws;
    const long SD = (long)kS * kD;            // 524288
    float* x      = ws;
    float* q      = ws + 1 * SD;
    float* kbuf   = ws + 2 * SD;
    float* v      = ws + 3 * SD;
    float* ao     = ws + 4 * SD;
    float* y      = ws + 5 * SD;
    float* hbuf   = ws + 6 * SD;              // 4*SD
    float* dist   = ws + 10 * SD;             // 2*SD
    float* scores = ws + 12 * SD;             // 16*SD
    float* bpw    = ws + 28 * SD;
    float* Atab   = bpw + 256;
    float* Btab   = Atab + 2080;
    float* partial= Btab + 2080;

    // bf16/f16 region
    unsigned short* ub = (unsigned short*)(ws + 28 * SD + 8512);
    unsigned short* xb   = ub;                       // 1024*1536
    unsigned short* aob  = xb   + 1572864;
    unsigned short* qb3  = aob  + 1572864;           // 8*1024*192
    unsigned short* kb3  = qb3  + 1572864;
    unsigned short* vtb  = kb3  + 1572864;           // 512*1024 (f16)
    unsigned short* Pb   = vtb  + 524288;            // 8*1024*1024 (f16)
    unsigned short* hb   = Pb   + 8388608;           // 1024*6144
    unsigned short* qwb  = hb   + 6291456;           // 2 x 512*1536
    unsigned short* kwb  = qwb  + 1572864;
    unsigned short* vwb  = kwb  + 1572864;
    unsigned short* owb  = vwb  + 1572864;
    unsigned short* f1wb = owb  + 1572864;           // 2 x 2048*1536
    unsigned short* f2wb = f1wb + 6291456;           // 2 x 512*6144

    // partial overlays (dead regions at time of use)
    float* part_big = scores;
    float* part_av  = hbuf;

    input_pe_k<<<kS, 256, 0, stream>>>(features, positions, fb, in_w, in_b, x);
    dist_k<<<kS, 256, 0, stream>>>(positions, dist);
    pwl_build_k<<<2, 256, 0, stream>>>(db1w, db1b, db2w, db2b, bpw, Atab, Btab);

    // weight transpose-splits (B-side layout [hi|hi|lo])
    split3_tr_k<<<dim3(16, 16, 2), 256, 0, stream>>>(qw, qwb, 512, 512, 262144, 786432);
    split3_tr_k<<<dim3(16, 16, 2), 256, 0, stream>>>(kw, kwb, 512, 512, 262144, 786432);
    split3_tr_k<<<dim3(16, 16, 2), 256, 0, stream>>>(vw, vwb, 512, 512, 262144, 786432);
    split3_tr_k<<<dim3(16, 16, 2), 256, 0, stream>>>(ow, owb, 512, 512, 262144, 786432);
    split3_tr_k<<<dim3(16, 64, 2), 256, 0, stream>>>(f1w, f1wb, 512, 2048, 1048576, 3145728);
    split3_tr_k<<<dim3(64, 16, 2), 256, 0, stream>>>(f2w, f2wb, 2048, 512, 1048576, 3145728);

    const long SS = (long)kS * kS;
    for (int l = 0; l < 2; ++l) {
        // x -> xb (A-side [hi|lo|hi])
        split3_rm_k<<<dim3(512, 1), 256, 0, stream>>>(x, xb, 524288, 9, 512, 0, 0, 0);
        // QKV: split-K x4
        bgemm_k<128, 0, 1, 0><<<dim3(8, 4, 12), 256, 0, stream>>>(
            xb, qwb + l * 786432, kwb + l * 786432, vwb + l * 786432,
            nullptr, 1024, 512, 384, 1536, 1536, 512, 0, 0, 0, 4,
            nullptr, nullptr, nullptr, nullptr, 0.f, part_big);
        reduce_k<0><<<dim3(512, 3), 256, 0, stream>>>(
            part_big, q, kbuf, v, qb + l * kD, kb + l * kD, vb + l * kD,
            kS, kD, 4, 0, kD, 1.f);

        // per-head splits: q A-side, k B-side; v -> f16 transposed x1024
        split3_rm_k<<<dim3(64, 8), 256, 0, stream>>>(q, qb3, 65536, 6, 512, 64, 196608, 0);
        split3_rm_k<<<dim3(64, 8), 256, 0, stream>>>(kbuf, kb3, 65536, 6, 512, 64, 196608, 1);
        tr_f16_k<<<dim3(32, 16), 256, 0, stream>>>(v, vtb, 1024, 512, 1024.f);

        // scores = (q@k^T)*scale + PWL-bias (3-term, K=192)
        bgemm_k<128, 2, 0, 0><<<dim3(8, 8, 8), 256, 0, stream>>>(
            qb3, kb3, kb3, kb3, scores,
            1024, 1024, 192, 192, 192, 1024, 196608, 196608, SS, 1,
            dist, bpw + l * 128, Atab + l * 1040, Btab + l * 1040, 0.125f, nullptr);
        softmax_k<<<kH * kS, 256, 0, stream>>>(scores);

        // P -> f16 x 2^14; attn@V in f16, split-K x4; reduce scales by 2^-24
        tof16_k<<<8192, 256, 0, stream>>>(scores, Pb, 8388608, 16384.f);
        bgemm_k<64, 0, 1, 1><<<dim3(8, 1, 32), 256, 0, stream>>>(
            Pb, vtb, vtb, vtb, nullptr,
            1024, 64, 256, 1024, 1024, 512, SS, 65536, 0, 4,
            nullptr, nullptr, nullptr, nullptr, 0.f, part_av);
        reduce_k<0><<<dim3(64, 8), 256, 0, stream>>>(
            part_av, ao, ao, ao, nullptr, nullptr, nullptr,
            kS, 64, 4, 64, kD, 1.f / 16777216.f);

        // O-proj: split-K x8
        split3_rm_k<<<dim3(512, 1), 256, 0, stream>>>(ao, aob, 524288, 9, 512, 0, 0, 0);
        bgemm_k<128, 0, 1, 0><<<dim3(8, 4, 8), 256, 0, stream>>>(
            aob, owb + l * 786432, owb + l * 786432, owb + l * 786432,
            nullptr, 1024, 512, 192, 1536, 1536, 512, 0, 0, 0, 8,
            nullptr, nullptr, nullptr, nullptr, 0.f, part_big);
        reduce_k<0><<<dim3(512, 1), 256, 0, stream>>>(
            part_big, y, y, y, ob + l * kD, ob + l * kD, ob + l * kD,
            kS, kD, 8, 0, kD, 1.f);
        add_ln_k<<<kS, 256, 0, stream>>>(x, y, n1g + l * kD, n1b + l * kD);

        // FFN1: split-K x2, relu in reduce
        const float* f1wl = f1w; (void)f1wl;
        split3_rm_k<<<dim3(512, 1), 256, 0, stream>>>(x, xb, 524288, 9, 512, 0, 0, 0);
        bgemm_k<128, 0, 1, 0><<<dim3(8, 16, 2), 256, 0, stream>>>(
            xb, f1wb + l * 3145728, f1wb + l * 3145728, f1wb + l * 3145728,
            nullptr, 1024, 2048, 768, 1536, 1536, 2048, 0, 0, 0, 2,
            nullptr, nullptr, nullptr, nullptr, 0.f, part_big);
        reduce_k<1><<<dim3(2048, 1), 256, 0, stream>>>(
            part_big, hbuf, hbuf, hbuf, f1b + l * kDFF, f1b + l * kDFF, f1b + l * kDFF,
            kS, kDFF, 2, 0, kDFF, 1.f);

        // FFN2: split-K x8
        split3_rm_k<<<dim3(2048, 1), 256, 0, stream>>>(hbuf, hb, 2097152, 11, 2048, 0, 0, 0);
        bgemm_k<128, 0, 1, 0><<<dim3(8, 4, 8), 256, 0, stream>>>(
            hb, f2wb + l * 3145728, f2wb + l * 3145728, f2wb + l * 3145728,
            nullptr, 1024, 512, 768, 6144, 6144, 512, 0, 0, 0, 8,
            nullptr, nullptr, nullptr, nullptr, 0.f, part_big);
        reduce_k<0><<<dim3(512, 1), 256, 0, stream>>>(
            part_big, y, y, y, f2b + l * kD, f2b + l * kD, f2b + l * kD,
            kS, kD, 8, 0, kD, 1.f);
        add_ln_k<<<kS, 256, 0, stream>>>(x, y, n2g + l * kD, n2b + l * kD);
    }

    pool_k<<<dim3(2, 8), 256, 0, stream>>>(x, partial);
    head_k<<<1, 256, 0, stream>>>(partial, c1w, c1b, c2w, c2b, (float*)d_out);
}